// Round 4
// baseline (595.199 us; speedup 1.0000x reference)
//
#include <hip/hip_runtime.h>
#include <hip/hip_bf16.h>

// ---------------------------------------------------------------------------
// MoE transformer block, MI355X gfx950.
// B=8 S=512 D=768 H=12 dh=64 E=14 K=4 HID=1536 SH=3072
// R9: counted-vmcnt pipeline, prefetch distance 2. R8's dbuf still drained
//     vmcnt(0) at every __syncthreads -> prefetch only got the ~150cy compute
//     window vs ~300-900cy load latency; pipes idle 60-70%. Now 3 LDS
//     buffers, raw s_barrier, s_waitcnt vmcnt(4) (last step vmcnt(0)):
//     stage-k loads fly across TWO barriers (~2 compute windows of cover).
//     Safety: stage k+2 overwrites buf (k-1)%3 only after barrier k, by
//     which point every wave's step-(k-1) ds_reads retired (lgkmcnt(0)
//     precedes its MFMAs in program order). sched_barrier(0) pins ordering.
//     LDS 48KB/block -> 3 blocks/CU (>= measured 2.3 avg residency).
//     Keeps: merged FFN1/FFN2, XCD grouping, w_k folded into FFN1 epilogue,
//     fast GELU, LDS attn, fused transpose.
// ---------------------------------------------------------------------------

typedef _Float16 f16x8 __attribute__((ext_vector_type(8)));
typedef float f32x4 __attribute__((ext_vector_type(4)));
typedef _Float16 f16;

// tanh-form GELU: one v_exp_f32; |diff vs erf-gelu| <= ~3e-3.
__device__ __forceinline__ float gelu_fast(float x) {
  const float k2l2e = 2.f * 0.7978845608028654f * 1.4426950408889634f;
  float u = (x + 0.044715f * x * x * x) * k2l2e;
  float t = exp2f(u);
  return x * (1.f - 1.f / (t + 1.f));
}

__device__ __forceinline__ f32x4 mfma16(f16x8 a, f16x8 b, f32x4 c) {
  return __builtin_amdgcn_mfma_f32_16x16x32_f16(a, b, c, 0, 0, 0);
}

// async global->LDS, 16B per lane; LDS dst must be wave-uniform base + lane*16
#define ASYNC_CP16(g, l)                                            \
  __builtin_amdgcn_global_load_lds(                                 \
      (const __attribute__((address_space(1))) void*)(g),           \
      (__attribute__((address_space(3))) void*)(l), 16, 0, 0)

// Stage one 128x32 A-tile and B-tile k-slice into LDS buffer `buf` (4 loads).
#define GEMM_STAGE(AB, WB, LDA, LDB, koff, buf)                               \
  ASYNC_CP16(&(AB)[(long)fr * (LDA) + (koff) + fc],        &sA[(buf) * 4096 + f]);        \
  ASYNC_CP16(&(AB)[(long)(fr + 64) * (LDA) + (koff) + fc], &sA[(buf) * 4096 + f + 2048]); \
  ASYNC_CP16(&(WB)[(long)fr * (LDB) + (koff) + fc],        &sB[(buf) * 4096 + f]);        \
  ASYNC_CP16(&(WB)[(long)(fr + 64) * (LDB) + (koff) + fc], &sB[(buf) * 4096 + f + 2048]);

// 3-buffer, distance-2 pipelined 128x128-tile GEMM K-loop with counted vmcnt.
// Per step k: vmcnt(4) [own stage-k loads done; stage-k+1's 4 still fly] ->
// s_barrier [all waves' stage-k done] -> issue stage k+2 into (k-1)%3 ->
// ds_read k%3 -> MFMA. Last step: vmcnt(0). Never drains in steady state.
// Requires in scope: sA,sB (f16[3*4096] LDS), f, fr, fc, wm, wn, lr, q4, acc.
#define GEMM_CORE(AB, WB, LDA, LDB, KK)                                       \
  {                                                                           \
    GEMM_STAGE(AB, WB, LDA, LDB, 0, 0)                                        \
    if ((KK) > 32) { GEMM_STAGE(AB, WB, LDA, LDB, 32, 1) }                    \
    int cur = 0;                                                              \
    for (int k0 = 0; k0 < (KK); k0 += 32) {                                   \
      if (k0 + 32 < (KK)) {                                                   \
        asm volatile("s_waitcnt vmcnt(4)" ::: "memory");                      \
      } else {                                                                \
        asm volatile("s_waitcnt vmcnt(0)" ::: "memory");                      \
      }                                                                       \
      __builtin_amdgcn_sched_barrier(0);                                      \
      __builtin_amdgcn_s_barrier();                                           \
      __builtin_amdgcn_sched_barrier(0);                                      \
      if (k0 + 64 < (KK)) {                                                   \
        const int nb = (cur + 2 >= 3) ? cur - 1 : cur + 2;                    \
        GEMM_STAGE(AB, WB, LDA, LDB, k0 + 64, nb)                             \
      }                                                                       \
      f16x8 av[4], bv[4];                                                     \
      _Pragma("unroll")                                                       \
      for (int i = 0; i < 4; i++)                                             \
        av[i] = *(const f16x8*)&sA[cur * 4096 + (wm + i * 16 + lr) * 32 + q4 * 8]; \
      _Pragma("unroll")                                                       \
      for (int j = 0; j < 4; j++)                                             \
        bv[j] = *(const f16x8*)&sB[cur * 4096 + (wn + j * 16 + lr) * 32 + q4 * 8]; \
      _Pragma("unroll")                                                       \
      for (int i = 0; i < 4; i++)                                             \
        _Pragma("unroll")                                                     \
        for (int j = 0; j < 4; j++) acc[i][j] = mfma16(av[i], bv[j], acc[i][j]); \
      __builtin_amdgcn_sched_barrier(0);                                      \
      cur = (cur == 2) ? 0 : cur + 1;                                         \
    }                                                                         \
  }

// ---------------------------------------------------------------------------
// LayerNorm: fp32 in -> f16 out, saves per-row mean and rstd (for router).
// ---------------------------------------------------------------------------
__global__ __launch_bounds__(256) void ln_kernel(
    const float* __restrict__ x, const float* __restrict__ g,
    const float* __restrict__ bt, f16* __restrict__ out,
    float* __restrict__ mout, float* __restrict__ rout)
{
  const int row = blockIdx.x;
  const float* xr = x + (long)row * 768;
  const int t = threadIdx.x;
  float v0 = xr[t], v1 = xr[t + 256], v2 = xr[t + 512];
  __shared__ float sb[8];
  float s = v0 + v1 + v2;
  #pragma unroll
  for (int o = 32; o > 0; o >>= 1) s += __shfl_xor(s, o, 64);
  const int w = t >> 6;
  if ((t & 63) == 0) sb[w] = s;
  __syncthreads();
  const float mean = (sb[0] + sb[1] + sb[2] + sb[3]) * (1.0f / 768.0f);
  const float d0 = v0 - mean, d1 = v1 - mean, d2 = v2 - mean;
  float q = d0 * d0 + d1 * d1 + d2 * d2;
  #pragma unroll
  for (int o = 32; o > 0; o >>= 1) q += __shfl_xor(q, o, 64);
  if ((t & 63) == 0) sb[4 + w] = q;
  __syncthreads();
  const float var = (sb[4] + sb[5] + sb[6] + sb[7]) * (1.0f / 768.0f);
  const float rstd = rsqrtf(var + 1e-5f);
  f16* orow = out + (long)row * 768;
  orow[t]       = (f16)(d0 * rstd * g[t]       + bt[t]);
  orow[t + 256] = (f16)(d1 * rstd * g[t + 256] + bt[t + 256]);
  orow[t + 512] = (f16)(d2 * rstd * g[t + 512] + bt[t + 512]);
  if (t == 0) { mout[row] = mean; rout[row] = rstd; }
}

// ---------------------------------------------------------------------------
// Fused transpose of all 6 weight matrices, fp32 [r][c] -> f16 [c][r].
// ---------------------------------------------------------------------------
struct TransArgs {
  const float* src[6];
  f16* dst[6];
  int rows[6], cols[6];
  int start[7];
};

__global__ __launch_bounds__(256) void transpose_all(TransArgs ta) {
  const int bid = blockIdx.x;
  int m = 0;
  #pragma unroll
  for (int i = 1; i < 6; i++) if (bid >= ta.start[i]) m = i;
  const int rows = ta.rows[m], cols = ta.cols[m];
  const int tilesC = cols >> 5;
  const int perB = (rows >> 5) * tilesC;
  int local = bid - ta.start[m];
  const int z = local / perB; local -= z * perB;
  const int tr = local / tilesC, tc = local - tr * tilesC;
  const float* inb = ta.src[m] + (long)z * rows * cols;
  f16* outb = ta.dst[m] + (long)z * rows * cols;
  const int c0 = tc * 32, r0 = tr * 32;
  __shared__ float tile[32][33];
  const int tx = threadIdx.x & 31, ty = threadIdx.x >> 5;
  #pragma unroll
  for (int i = 0; i < 32; i += 8)
    tile[ty + i][tx] = inb[(long)(r0 + ty + i) * cols + c0 + tx];
  __syncthreads();
  #pragma unroll
  for (int i = 0; i < 32; i += 8)
    outb[(long)(c0 + ty + i) * rows + r0 + tx] = (f16)tile[tx][ty + i];
}

// ---------------------------------------------------------------------------
// Generic GEMM: C[M,N] = A[M,K] @ W^T   (A f16 row-major, W f16 [N][K]).
// 128x128 tile, BK=32, 4 waves x 64x64. Distance-2 pipelined staging.
// ---------------------------------------------------------------------------
#define EPI_QKV     0
#define EPI_RESID   1

template <int EPI>
__global__ __launch_bounds__(256) void gemm_bt(
    const f16* __restrict__ A, int K, long strideA, int aShift,
    const f16* __restrict__ W, long strideW,
    const float* __restrict__ bias, int strideBias,
    const int* __restrict__ topkIdx,
    void* __restrict__ outv, long strideOut, int ldout,
    const float* __restrict__ resid)
{
  __shared__ f16 sA[3 * 128 * 32];
  __shared__ f16 sB[3 * 128 * 32];
  const int tid = threadIdx.x;
  const int pair = blockIdx.z;
  const int m0 = blockIdx.y * 128;
  const int n0 = blockIdx.x * 128;
  const f16* Ab = A + ((long)(pair >> aShift)) * strideA + (long)m0 * K;
  const int wsel = topkIdx ? topkIdx[pair] : pair;
  const f16* Wb = W + (long)wsel * strideW + (long)n0 * K;

  const int f = tid * 8;
  const int fr = f >> 5;
  const int fc = f & 31;
  const int lane = tid & 63, wid = tid >> 6;
  const int wm = (wid >> 1) * 64, wn = (wid & 1) * 64;
  const int lr = lane & 15, q4 = lane >> 4;

  f32x4 zero = {0.f, 0.f, 0.f, 0.f};
  f32x4 acc[4][4];
  #pragma unroll
  for (int i = 0; i < 4; i++)
    #pragma unroll
    for (int j = 0; j < 4; j++) acc[i][j] = zero;

  GEMM_CORE(Ab, Wb, K, K, K);

  // Epilogue. C/D layout: col = lane&15, row = (lane>>4)*4 + reg.
  #pragma unroll
  for (int i = 0; i < 4; i++) {
    #pragma unroll
    for (int j = 0; j < 4; j++) {
      #pragma unroll
      for (int r = 0; r < 4; r++) {
        const int row = m0 + wm + i * 16 + q4 * 4 + r;
        const int col = n0 + wn + j * 16 + lr;
        float v = acc[i][j][r];
        if constexpr (EPI == EPI_QKV) {
          f16* qb = (f16*)outv;
          const int i3 = col / 768;
          const int rem = col - i3 * 768;
          const int hh = rem >> 6, dd = rem & 63;
          const int bb = row >> 9, ss = row & 511;
          const long bh = bb * 12 + hh;
          if (i3 == 0)      qb[(bh * 512 + ss) * 64 + dd] = (f16)v;           // Q
          else if (i3 == 1) qb[3145728 + (bh * 512 + ss) * 64 + dd] = (f16)v; // K
          else              qb[6291456 + (bh * 64 + dd) * 512 + ss] = (f16)v; // V^T
        } else {  // EPI_RESID
          float* ob = (float*)outv;
          v += bias[col];
          ob[(long)row * ldout + col] = resid[(long)row * ldout + col] + v;
        }
      }
    }
  }
}

// ---------------------------------------------------------------------------
// Merged FFN1: shared FFN1 (768 blocks) + expert FFN1 (1536 blocks), K=768.
// Per-XCD role split; consecutive same-A blocks stay on one XCD for L2 reuse.
//   shared: shid[row][col] = gelu(hbuf@shw1t + shb1)
//   expert: hid[pair][row][col] = gelu(hbuf_b@ew1t[e] + eb1[e]) * w_k
// ---------------------------------------------------------------------------
__global__ __launch_bounds__(256) void gemm_ffn1(
    const f16* __restrict__ hbuf,
    const f16* __restrict__ shw1t, const float* __restrict__ shb1,
    const f16* __restrict__ ew1t,  const float* __restrict__ eb1,
    const int* __restrict__ topk,  const float* __restrict__ wslot,
    f16* __restrict__ shid, f16* __restrict__ hid)
{
  __shared__ f16 sA[3 * 128 * 32];
  __shared__ f16 sB[3 * 128 * 32];
  const int orig = blockIdx.x;          // 2304 = 8 XCDs x 288
  const int xcd = orig & 7, slot = orig >> 3;

  const int tid = threadIdx.x;
  const int f = tid * 8;
  const int fr = f >> 5, fc = f & 31;
  const int lane = tid & 63, wid = tid >> 6;
  const int wm = (wid >> 1) * 64, wn = (wid & 1) * 64;
  const int lr = lane & 15, q4 = lane >> 4;

  const f16* Ab;
  const f16* Wb;
  const float* bp;
  f16* outp;
  int ldo;
  float wscale;

  if (slot < 96) {                      // shared role: l in [0,768)
    const int l = xcd * 96 + slot;
    const int bx = l % 24, by = l / 24; // n-tile 0..23, m-tile 0..31
    const int n0 = bx * 128, m0 = by * 128;
    Ab = hbuf + (long)m0 * 768;
    Wb = shw1t + (long)n0 * 768;
    bp = shb1 + n0;
    outp = shid + (long)m0 * 3072 + n0;
    ldo = 3072;
    wscale = 1.f;
  } else {                              // expert role: l in [0,1536)
    const int l = xcd * 192 + (slot - 96);
    const int bx = l % 12;
    const int u = l / 12;
    const int by = u & 3, pair = u >> 2;
    const int wsel = topk[pair];
    const int n0 = bx * 128;
    const int m0g = (pair >> 2) * 512 + by * 128;   // global row in hbuf
    Ab = hbuf + (long)m0g * 768;
    Wb = ew1t + (long)wsel * (1536L * 768) + (long)n0 * 768;
    bp = eb1 + (long)wsel * 1536 + n0;
    outp = hid + (long)pair * (512L * 1536) + (long)(by * 128) * 1536 + n0;
    ldo = 1536;
    wscale = wslot[pair];
  }

  f32x4 zero = {0.f, 0.f, 0.f, 0.f};
  f32x4 acc[4][4];
  #pragma unroll
  for (int i = 0; i < 4; i++)
    #pragma unroll
    for (int j = 0; j < 4; j++) acc[i][j] = zero;

  GEMM_CORE(Ab, Wb, 768, 768, 768);

  #pragma unroll
  for (int i = 0; i < 4; i++)
    #pragma unroll
    for (int j = 0; j < 4; j++)
      #pragma unroll
      for (int r = 0; r < 4; r++) {
        const int rr = wm + i * 16 + q4 * 4 + r;
        const int cc = wn + j * 16 + lr;
        float v = acc[i][j][r] + bp[cc];
        outp[(long)rr * ldo + cc] = (f16)(gelu_fast(v) * wscale);
      }
}

// ---------------------------------------------------------------------------
// Merged FFN2: shared FFN2 (192 blocks, K=3072) + expert FFN2 (768 blocks,
// K=1536) in one 960-block launch. Per-XCD chunk: 24 long + 96 short blocks,
// long blocks at low orig -> dispatched first (no long-tail).
//   shared: dout[row][col] = x2 + shid@shw2t + shb2         (fp32)
//   expert: eo[pair][row][col] = hid@ew2t[e] + w_k*eb2[e]   (f16)
// ---------------------------------------------------------------------------
__global__ __launch_bounds__(256) void gemm_ffn2(
    const f16* __restrict__ shid, const f16* __restrict__ shw2t,
    const float* __restrict__ shb2, const float* __restrict__ x2,
    const f16* __restrict__ hid, const f16* __restrict__ ew2t,
    const float* __restrict__ eb2,
    const int* __restrict__ topk, const float* __restrict__ wslot,
    float* __restrict__ dout, f16* __restrict__ eo)
{
  __shared__ f16 sA[3 * 128 * 32];
  __shared__ f16 sB[3 * 128 * 32];
  const int orig = blockIdx.x;          // 960 = 8 XCDs x 120
  const int xcd = orig & 7, slot = orig >> 3;

  const int tid = threadIdx.x;
  const int f = tid * 8;
  const int fr = f >> 5, fc = f & 31;
  const int lane = tid & 63, wid = tid >> 6;
  const int wm = (wid >> 1) * 64, wn = (wid & 1) * 64;
  const int lr = lane & 15, q4 = lane >> 4;

  const bool shared_role = (slot < 24);
  const f16* Ab;
  const f16* Wb;
  int K, m0, n0, pair = 0, wsel = 0;

  if (shared_role) {                    // l in [0,192)
    const int l = xcd * 24 + slot;
    const int bx = l % 6, by = l / 6;   // n-tile 0..5, m-tile 0..31
    n0 = bx * 128; m0 = by * 128;
    K = 3072;
    Ab = shid + (long)m0 * 3072;
    Wb = shw2t + (long)n0 * 3072;
  } else {                              // l in [0,768)
    const int l = xcd * 96 + (slot - 24);
    const int bx = l % 6;
    const int u = l / 6;
    const int by = u & 3; pair = u >> 2;
    wsel = topk[pair];
    n0 = bx * 128; m0 = by * 128;       // m0 local within 512-row slot
    K = 1536;
    Ab = hid + (long)pair * (512L * 1536) + (long)m0 * 1536;
    Wb = ew2t + (long)wsel * (768L * 1536) + (long)n0 * 1536;
  }

  f32x4 zero = {0.f, 0.f, 0.f, 0.f};
  f32x4 acc[4][4];
  #pragma unroll
  for (int i = 0; i < 4; i++)
    #pragma unroll
    for (int j = 0; j < 4; j++) acc[i][j] = zero;

  if (shared_role) {
    GEMM_CORE(Ab, Wb, 3072, 3072, 3072);
  } else {
    GEMM_CORE(Ab, Wb, 1536, 1536, 1536);
  }

  if (shared_role) {
    float* op = dout + (long)m0 * 768 + n0;
    const float* rp = x2 + (long)m0 * 768 + n0;
    const float* bp = shb2 + n0;
    #pragma unroll
    for (int i = 0; i < 4; i++)
      #pragma unroll
      for (int j = 0; j < 4; j++)
        #pragma unroll
        for (int r = 0; r < 4; r++) {
          const int rr = wm + i * 16 + q4 * 4 + r;
          const int cc = wn + j * 16 + lr;
          op[(long)rr * 768 + cc] = rp[(long)rr * 768 + cc] + acc[i][j][r] + bp[cc];
        }
  } else {
    const float wscale = wslot[pair];
    f16* op = eo + (long)pair * (512L * 768) + (long)m0 * 768 + n0;
    const float* bp = eb2 + (long)wsel * 768 + n0;
    #pragma unroll
    for (int i = 0; i < 4; i++)
      #pragma unroll
      for (int j = 0; j < 4; j++)
        #pragma unroll
        for (int r = 0; r < 4; r++) {
          const int rr = wm + i * 16 + q4 * 4 + r;
          const int cc = wn + j * 16 + lr;
          op[(long)rr * 768 + cc] = (f16)(acc[i][j][r] + wscale * bp[cc]);
        }
  }
}

// ---------------------------------------------------------------------------
// Fused attention per (b*h, q-tile of 64). P lives in LDS (XOR-swizzled);
// each wave touches only its own 16 q-rows -> no barrier needed.
// ---------------------------------------------------------------------------
__device__ __forceinline__ int pswz(int row, int col) {
  return row * 512 + (col ^ ((row & 7) << 3));
}

__global__ __launch_bounds__(256) void attn_kernel(
    const f16* __restrict__ Q, const f16* __restrict__ Kt,
    const f16* __restrict__ Vt, f16* __restrict__ AO)
{
  __shared__ f16 Ps[64 * 512];
  const int bh = blockIdx.x;
  const int qt = blockIdx.y;
  const int t = threadIdx.x;
  const int lane = t & 63, w = t >> 6;
  const int lr = lane & 15, q4 = lane >> 4;
  const int r0 = qt * 64 + w * 16;
  const int lrow0 = w * 16;
  const f16* Qh = Q + (long)bh * 512 * 64;
  const f16* Kh = Kt + (long)bh * 512 * 64;

  f32x4 zero = {0.f, 0.f, 0.f, 0.f};
  f32x4 acc[32];
  #pragma unroll
  for (int i = 0; i < 32; i++) acc[i] = zero;

  #pragma unroll
  for (int kk = 0; kk < 2; kk++) {
    f16x8 a = *(const f16x8*)&Qh[(r0 + lr) * 64 + kk * 32 + q4 * 8];
    #pragma unroll
    for (int nt = 0; nt < 32; nt++) {
      f16x8 b = *(const f16x8*)&Kh[(nt * 16 + lr) * 64 + kk * 32 + q4 * 8];
      acc[nt] = mfma16(a, b, acc[nt]);
    }
  }

  const float cscale = 0.125f * 1.44269504089f;
  #pragma unroll
  for (int r = 0; r < 4; r++) {
    float m = -1e30f;
    #pragma unroll
    for (int nt = 0; nt < 32; nt++) m = fmaxf(m, acc[nt][r]);
    #pragma unroll
    for (int o = 1; o < 16; o <<= 1) m = fmaxf(m, __shfl_xor(m, o, 64));
    float s = 0.f;
    #pragma unroll
    for (int nt = 0; nt < 32; nt++) {
      float e = exp2f((acc[nt][r] - m) * cscale);
      acc[nt][r] = e; s += e;
    }
    #pragma unroll
    for (int o = 1; o < 16; o <<= 1) s += __shfl_xor(s, o, 64);
    const float inv = 1.f / s;
    const int lrow = lrow0 + q4 * 4 + r;
    #pragma unroll
    for (int nt = 0; nt < 32; nt++)
      Ps[pswz(lrow, nt * 16 + lr)] = (f16)(acc[nt][r] * inv);
  }

  const f16* Vh = Vt + (long)bh * 64 * 512;
  f32x4 o4[4];
  #pragma unroll
  for (int i = 0; i < 4; i++) o4[i] = zero;
  #pragma unroll
  for (int kk = 0; kk < 16; kk++) {
    f16x8 a = *(const f16x8*)&Ps[pswz(lrow0 + lr, kk * 32 + q4 * 8)];
    #pragma unroll
    for (int nt = 0; nt < 4; nt++) {
      f16x8 b = *(const f16x8*)&Vh[(nt * 16 + lr) * 512 + kk * 32 + q4 * 8];
      o4[nt] = mfma16(a, b, o4[nt]);
    }
  }
  const int b_ = bh / 12, h_ = bh - b_ * 12;
  #pragma unroll
  for (int nt = 0; nt < 4; nt++)
    #pragma unroll
    for (int r = 0; r < 4; r++) {
      const int rowg = r0 + q4 * 4 + r;
      AO[((long)(b_ * 512 + rowg)) * 768 + h_ * 64 + nt * 16 + lr] = (f16)o4[nt][r];
    }
}

// ---------------------------------------------------------------------------
// Router stage 1: partial sums of (x-m)*r over 32-row chunks. part[b][c][768].
// ---------------------------------------------------------------------------
__global__ __launch_bounds__(256) void router_reduce(
    const float* __restrict__ x2, const float* __restrict__ lnm,
    const float* __restrict__ lnr, float* __restrict__ part)
{
  const int c = blockIdx.x, b = blockIdx.y, t = threadIdx.x;
  float a0 = 0.f, a1 = 0.f, a2 = 0.f;
  #pragma unroll 4
  for (int s = 0; s < 32; s++) {
    const long base = (long)b * 512 + c * 32 + s;
    const float m = lnm[base], r = lnr[base];
    const float* xr = x2 + base * 768;
    a0 += (xr[t] - m) * r;
    a1 += (xr[t + 256] - m) * r;
    a2 += (xr[t + 512] - m) * r;
  }
  float* pr = part + ((long)b * 16 + c) * 768;
  pr[t] = a0; pr[t + 256] = a1; pr[t + 512] = a2;
}

// ---------------------------------------------------------------------------
// Router stage 2: fold partials -> seq_repr (fp32, global).
// ---------------------------------------------------------------------------
__global__ __launch_bounds__(256) void router_seq(
    const float* __restrict__ part, const float* __restrict__ g2,
    const float* __restrict__ b2ln, float* __restrict__ seqg)
{
  const int b = blockIdx.x, t = threadIdx.x;
  const float* pb = part + (long)b * 16 * 768;
  #pragma unroll
  for (int i = 0; i < 3; i++) {
    const int j = t + 256 * i;
    float a = 0.f;
    #pragma unroll
    for (int c = 0; c < 16; c++) a += pb[c * 768 + j];
    seqg[b * 768 + j] = a * (1.f / 512.f) * g2[j] + b2ln[j];
  }
}

// ---------------------------------------------------------------------------
// Router stage 3: MLP1 partials over 48-deep d-slices.
// ---------------------------------------------------------------------------
__global__ __launch_bounds__(256) void router_mlp1(
    const float* __restrict__ seqg, const float* __restrict__ rw1,
    float* __restrict__ pmlp)
{
  const int c = blockIdx.x, b = blockIdx.y, t = threadIdx.x;
  const float* sq = seqg + b * 768 + c * 48;
  float a0 = 0.f, a1 = 0.f, a2 = 0.f;
  #pragma unroll 8
  for (int d = 0; d < 48; d++) {
    const float s = sq[d];
    const float* wr = rw1 + (long)(c * 48 + d) * 768;
    a0 += s * wr[t];
    a1 += s * wr[t + 256];
    a2 += s * wr[t + 512];
  }
  float* pr = pmlp + ((long)b * 16 + c) * 768;
  pr[t] = a0; pr[t + 256] = a1; pr[t + 512] = a2;
}

// ---------------------------------------------------------------------------
// Router stage 4: fold MLP1 partials + bias + gelu (exact fp32) -> g1g.
// ---------------------------------------------------------------------------
__global__ __launch_bounds__(256) void router_fold(
    const float* __restrict__ pmlp, const float* __restrict__ rb1,
    float* __restrict__ g1g)
{
  const int b = blockIdx.x, t = threadIdx.x;
  const float* pb = pmlp + (long)b * 16 * 768;
  #pragma unroll
  for (int i = 0; i < 3; i++) {
    const int j = t + 256 * i;
    float a = rb1[j];
    #pragma unroll
    for (int c = 0; c < 16; c++) a += pb[c * 768 + j];
    g1g[b * 768 + j] = 0.5f * a * (1.0f + erff(a * 0.70710678118654752f));
  }
}

// ---------------------------------------------------------------------------
// Router stage 5: logits; softmax; top4; renorm (fp32 exact selection).
// ---------------------------------------------------------------------------
__global__ __launch_bounds__(256) void router_top(
    const float* __restrict__ g1g, const float* __restrict__ rw2,
    const float* __restrict__ rb2, float* __restrict__ wslot,
    int* __restrict__ topkIdx)
{
  __shared__ float lg[14];
  const int b = blockIdx.x, t = threadIdx.x;
  const int e = t >> 4, sub = t & 15;
  if (e < 14) {
    float a = 0.f;
    #pragma unroll
    for (int i = 0; i < 48; i++) {
      const int d = sub + 16 * i;
      a += g1g[b * 768 + d] * rw2[d * 14 + e];
    }
    #pragma unroll
    for (int o = 1; o < 16; o <<= 1) a += __shfl_xor(a, o, 64);
    if (sub == 0) lg[e] = a + rb2[e];
  }
  __syncthreads();
  if (t == 0) {
    float mx = -1e30f;
    for (int ee = 0; ee < 14; ee++) mx = fmaxf(mx, lg[ee]);
    float p[14], s = 0.f;
    for (int ee = 0; ee < 14; ee++) { p[ee] = expf(lg[ee] - mx); s += p[ee]; }
    for (int ee = 0; ee < 14; ee++) p[ee] /= s;
    int idx[4]; float val[4]; bool used[14];
    for (int ee = 0; ee < 14; ee++) used[ee] = false;
    for (int k = 0; k < 4; k++) {
      int best = -1; float bv = -1.f;
      for (int ee = 0; ee < 14; ee++)
        if (!used[ee] && p[ee] > bv) { bv = p[ee]; best = ee; }
      used[best] = true; idx[k] = best; val[k] = bv;
    }
    const float m2 = val[0];
    float ss = 0.f, e4[4];
    for (int k = 0; k < 4; k++) { e4[k] = expf(val[k] - m2); ss += e4[k]; }
    for (int k = 0; k < 4; k++) {
      wslot[b * 4 + k] = e4[k] / ss;
      topkIdx[b * 4 + k] = idx[k];
    }
  }
}

// ---------------------------------------------------------------------------
// Final combine: out += eo0+eo1+eo2+eo3 (out already = x2 + shared + bias).
// ---------------------------------------------------------------------------
__global__ __launch_bounds__(256) void combine_kernel(
    const f16* __restrict__ eo, float* __restrict__ out)
{
  const long i = (long)blockIdx.x * 256 + threadIdx.x;
  const long b = i / (512L * 768);
  const long loc = i - b * (512L * 768);
  const f16* e0 = eo + b * 4 * (512L * 768) + loc;
  float v = out[i];
  v += (float)e0[0] + (float)e0[512L * 768] + (float)e0[2 * 512L * 768] +
       (float)e0[3 * 512L * 768];
  out[i] = v;
}

// ---------------------------------------------------------------------------
// Workspace layout (bytes). Weights persistent; activations alias.
// Total ~191.5 MB.
// ---------------------------------------------------------------------------
static const long OFF_X2    = 0L;                       // 12582912
static const long OFF_LNM   = 12582912L;
static const long OFF_LNR   = OFF_LNM + 16384L;
static const long OFF_WSLOT = OFF_LNR + 16384L;
static const long OFF_TOPK  = OFF_WSLOT + 256L;
static const long OFF_PART  = OFF_TOPK + 256L;          // 393216
static const long OFF_SEQG  = OFF_PART + 393216L;
static const long OFF_PMLP  = OFF_SEQG + 24576L;
static const long OFF_G1G   = OFF_PMLP + 393216L;       // ends 13451776
// persistent transposed weights
static const long W_QKVWT  = 13631488L;                 // 3538944
static const long W_PROJWT = W_QKVWT + 3538944L;        // 1179648
static const long W_EW1T   = W_PROJWT + 1179648L;       // 33030144
static const long W_EW2T   = W_EW1T + 33030144L;        // 33030144
static const long W_SHW1T  = W_EW2T + 33030144L;        // 4718592
static const long W_SHW2T  = W_SHW1T + 4718592L;        // 4718592 -> 93847552
// activation region (phase A aliases phase B)
static const long OFF_ACT  = 93847552L;
static const long A_H1     = OFF_ACT;                   // 6291456
static const long A_Q      = OFF_ACT + 6291456L;        // 3 x 6291456
static const long A_AO     = A_Q + 18874368L;           // 6291456
static const long B_H      = OFF_ACT;                   // 6291456
static const long B_HID    = OFF_ACT + 6291456L;        // 50331648
static const long B_SHID   = B_HID + 50331648L;         // 25165824
static const long B_EO     = B_SHID + 25165824L;        // 25165824 -> ends 200802304

extern "C" void kernel_launch(void* const* d_in, const int* in_sizes, int n_in,
                              void* d_out, int out_size, void* d_ws, size_t ws_size,
                              hipStream_t stream) {
  const float* x     = (const float*)d_in[0];
  const float* ln1g  = (const float*)d_in[1];
  const float* ln1b  = (const float*)d_in[2];
  const float* qkvw  = (const float*)d_in[3];
  const float* projw = (const float*)d_in[4];
  const float* projb = (const float*)d_in[5];
  const float* ln2g  = (const float*)d_in[6];
  const float* ln2b  = (const float*)d_in[7];
  const float* rw1   = (const float*)d_in[8];
  const float* rb1   = (const float*)d_in[9];
  const float* rw2   = (const float*)d_in[10];
  const float* rb2   = (const float*)d_in[11];
  const float* ew1   = (const float*)d_in[12];
  const float* eb1   = (const float*)d_in[13];
  const float* ew2   = (const float*)d_in[14];
  const float* eb2   = (const float*)d_in[15];
  const float* shw1  = (const float*)d_in[16];
  const float* shb1  = (const float*)d_in[17];
  const float* shw2  = (const float*)d_in[18];
  const float* shb2  = (const float*)d_in[19];

  char* ws = (char*)d_ws;
  float* x2    = (float*)(ws + OFF_X2);
  float* lnm   = (float*)(ws + OFF_LNM);
  float* lnr   = (float*)(ws + OFF_LNR);
  float* wslot = (float*)(ws + OFF_WSLOT);
  int*   topk  = (int*)(ws + OFF_TOPK);
  float* part  = (float*)(ws + OFF_PART);
  float* seqg  = (float*)(ws + OFF_SEQG);
  float* pmlp  = (float*)(ws + OFF_PMLP);
  float* g1g   = (float*)(ws + OFF_G1G);
  f16* qkvwt  = (f16*)(ws + W_QKVWT);
  f16* projwt = (f16*)(ws + W_PROJWT);
  f16* ew1t   = (f16*)(ws + W_EW1T);
  f16* ew2t   = (f16*)(ws + W_EW2T);
  f16* shw1t  = (f16*)(ws + W_SHW1T);
  f16* shw2t  = (f16*)(ws + W_SHW2T);
  f16* h1     = (f16*)(ws + A_H1);
  f16* Qb     = (f16*)(ws + A_Q);
  f16* aob    = (f16*)(ws + A_AO);
  f16* hbuf   = (f16*)(ws + B_H);
  f16* hid    = (f16*)(ws + B_HID);
  f16* shid   = (f16*)(ws + B_SHID);
  f16* eo     = (f16*)(ws + B_EO);

  // ---- all weight transposes in one launch ----
  TransArgs ta;
  ta.src[0] = qkvw;  ta.dst[0] = qkvwt;  ta.rows[0] = 768;  ta.cols[0] = 2304;
  ta.src[1] = projw; ta.dst[1] = projwt; ta.rows[1] = 768;  ta.cols[1] = 768;
  ta.src[2] = ew1;   ta.dst[2] = ew1t;   ta.rows[2] = 768;  ta.cols[2] = 1536;
  ta.src[3] = ew2;   ta.dst[3] = ew2t;   ta.rows[3] = 1536; ta.cols[3] = 768;
  ta.src[4] = shw1;  ta.dst[4] = shw1t;  ta.rows[4] = 768;  ta.cols[4] = 3072;
  ta.src[5] = shw2;  ta.dst[5] = shw2t;  ta.rows[5] = 3072; ta.cols[5] = 768;
  ta.start[0] = 0;     ta.start[1] = 1728;  ta.start[2] = 2304;
  ta.start[3] = 18432; ta.start[4] = 34560; ta.start[5] = 36864;
  ta.start[6] = 39168;
  transpose_all<<<39168, 256, 0, stream>>>(ta);

  // ---- Phase A: attention ----
  ln_kernel<<<4096, 256, 0, stream>>>(x, ln1g, ln1b, h1, lnm, lnr);
  gemm_bt<EPI_QKV><<<dim3(18, 32, 1), 256, 0, stream>>>(
      h1, 768, 0, 0, qkvwt, 0, nullptr, 0, nullptr, (void*)Qb, 0, 0, nullptr);
  attn_kernel<<<dim3(96, 8, 1), 256, 0, stream>>>(Qb, Qb + 3145728, Qb + 6291456, aob);
  gemm_bt<EPI_RESID><<<dim3(6, 32, 1), 256, 0, stream>>>(
      aob, 768, 0, 0, projwt, 0, projb, 0, nullptr, (void*)x2, 0, 768, x);

  // ---- Phase B: MoE ----
  ln_kernel<<<4096, 256, 0, stream>>>(x2, ln2g, ln2b, hbuf, lnm, lnr);
  router_reduce<<<dim3(16, 8, 1), 256, 0, stream>>>(x2, lnm, lnr, part);
  router_seq<<<8, 256, 0, stream>>>(part, ln2g, ln2b, seqg);
  router_mlp1<<<dim3(16, 8, 1), 256, 0, stream>>>(seqg, rw1, pmlp);
  router_fold<<<8, 256, 0, stream>>>(pmlp, rb1, g1g);
  router_top<<<8, 256, 0, stream>>>(g1g, rw2, rb2, wslot, topk);
  // merged FFN1: shared (768 blocks) + expert (1536 blocks), K=768 uniform
  gemm_ffn1<<<2304, 256, 0, stream>>>(hbuf, shw1t, shb1, ew1t, eb1,
                                      topk, wslot, shid, hid);
  // merged FFN2: shared (192 blocks, K=3072) + expert (768 blocks, K=1536)
  gemm_ffn2<<<960, 256, 0, stream>>>(shid, shw2t, shb2, x2, hid, ew2t, eb2,
                                     topk, wslot, (float*)d_out, eo);
  combine_kernel<<<12288, 256, 0, stream>>>(eo, (float*)d_out);
}

// Round 5
// 583.855 us; speedup vs baseline: 1.0194x; 1.0194x over previous
//
#include <hip/hip_runtime.h>
#include <hip/hip_bf16.h>

// ---------------------------------------------------------------------------
// MoE transformer block, MI355X gfx950.
// B=8 S=512 D=768 H=12 dh=64 E=14 K=4 HID=1536 SH=3072
// R10: (1) ffn1 uses fixed distance-2 counted-vmcnt core: sched_barrier(0)
//      only after s_barrier; loop tail uses sched_barrier(0x38F) = block
//      VMEM crossing only (protects vmcnt count from hoisted epilogue
//      loads) while VALU/MFMA/DS stay free (R9's full pin killed ILP:
//      VALUBusy 38->14). (2) ffn2 reverts to R8 dbuf core (R9 hurt it
//      114 vs <=108). (3) Vectorized epilogues: acc -> LDS scratch (reuse
//      staging LDS) -> 16B coalesced stores, replacing 64 scalar 2B
//      stores/thread; ffn2-shared = two 64-row fp32 passes w/ vector
//      resid+bias. combine vectorized (f16x4/float4).
//      Keeps: merged FFN1/FFN2 grids, XCD grouping, w_k in FFN1 epilogue,
//      fast GELU, LDS attn, fused transpose.
// ---------------------------------------------------------------------------

typedef _Float16 f16x8 __attribute__((ext_vector_type(8)));
typedef _Float16 f16x4 __attribute__((ext_vector_type(4)));
typedef float f32x4 __attribute__((ext_vector_type(4)));
typedef _Float16 f16;

// tanh-form GELU: one v_exp_f32; |diff vs erf-gelu| <= ~3e-3.
__device__ __forceinline__ float gelu_fast(float x) {
  const float k2l2e = 2.f * 0.7978845608028654f * 1.4426950408889634f;
  float u = (x + 0.044715f * x * x * x) * k2l2e;
  float t = exp2f(u);
  return x * (1.f - 1.f / (t + 1.f));
}

__device__ __forceinline__ f32x4 mfma16(f16x8 a, f16x8 b, f32x4 c) {
  return __builtin_amdgcn_mfma_f32_16x16x32_f16(a, b, c, 0, 0, 0);
}

// async global->LDS, 16B per lane; LDS dst must be wave-uniform base + lane*16
#define ASYNC_CP16(g, l)                                            \
  __builtin_amdgcn_global_load_lds(                                 \
      (const __attribute__((address_space(1))) void*)(g),           \
      (__attribute__((address_space(3))) void*)(l), 16, 0, 0)

// Stage one 128x32 A-tile and B-tile k-slice into LDS buffer `buf` (4 loads).
#define GEMM_STAGE(AB, WB, LDA, LDB, koff, buf)                               \
  ASYNC_CP16(&(AB)[(long)fr * (LDA) + (koff) + fc],        &sA[(buf) * 4096 + f]);        \
  ASYNC_CP16(&(AB)[(long)(fr + 64) * (LDA) + (koff) + fc], &sA[(buf) * 4096 + f + 2048]); \
  ASYNC_CP16(&(WB)[(long)fr * (LDB) + (koff) + fc],        &sB[(buf) * 4096 + f]);        \
  ASYNC_CP16(&(WB)[(long)(fr + 64) * (LDB) + (koff) + fc], &sB[(buf) * 4096 + f + 2048]);

// R8-proven double-buffered core: per K-step {ds_read cur | prefetch k+32
// into cur^1 | MFMA | __syncthreads}. Prefetch overlaps the compute window.
#define GEMM_CORE2(AB, WB, LDA, LDB, KK)                                      \
  {                                                                           \
    GEMM_STAGE(AB, WB, LDA, LDB, 0, 0)                                        \
    __syncthreads();                                                          \
    int cur = 0;                                                              \
    for (int k0 = 0; k0 < (KK); k0 += 32) {                                   \
      f16x8 av[4], bv[4];                                                     \
      _Pragma("unroll")                                                       \
      for (int i = 0; i < 4; i++)                                             \
        av[i] = *(const f16x8*)&sA[cur * 4096 + (wm + i * 16 + lr) * 32 + q4 * 8]; \
      _Pragma("unroll")                                                       \
      for (int j = 0; j < 4; j++)                                             \
        bv[j] = *(const f16x8*)&sB[cur * 4096 + (wn + j * 16 + lr) * 32 + q4 * 8]; \
      if (k0 + 32 < (KK)) {                                                   \
        GEMM_STAGE(AB, WB, LDA, LDB, k0 + 32, cur ^ 1)                        \
      }                                                                       \
      _Pragma("unroll")                                                       \
      for (int i = 0; i < 4; i++)                                             \
        _Pragma("unroll")                                                     \
        for (int j = 0; j < 4; j++) acc[i][j] = mfma16(av[i], bv[j], acc[i][j]); \
      if (k0 + 32 < (KK)) __syncthreads();                                    \
      cur ^= 1;                                                               \
    }                                                                         \
  }

// Distance-2 pipelined core (3 buffers, counted vmcnt). Per step k:
//   vmcnt(4) [stage-k complete, stage-k+1 still flying] -> s_barrier ->
//   sched_barrier(0) [ds_reads pinned below barrier] -> issue stage k+2
//   into (k-1)%3 -> ds_read k%3 -> MFMA -> sched_barrier(0x38F)
//   [VMEM may not cross: keeps vmcnt counting exact; VALU/MFMA/DS free].
// Buffer-overwrite safety: stage k+2 lands in buf(k-1); all waves' step-k-1
// ds_reads completed before barrier k (lgkmcnt precedes their MFMAs).
#define GEMM_CORE3(AB, WB, LDA, LDB, KK)                                      \
  {                                                                           \
    GEMM_STAGE(AB, WB, LDA, LDB, 0, 0)                                        \
    GEMM_STAGE(AB, WB, LDA, LDB, 32, 1)                                       \
    int cur = 0;                                                              \
    for (int k0 = 0; k0 < (KK); k0 += 32) {                                   \
      if (k0 + 32 < (KK)) {                                                   \
        asm volatile("s_waitcnt vmcnt(4)" ::: "memory");                      \
      } else {                                                                \
        asm volatile("s_waitcnt vmcnt(0)" ::: "memory");                      \
      }                                                                       \
      __builtin_amdgcn_s_barrier();                                           \
      __builtin_amdgcn_sched_barrier(0);                                      \
      if (k0 + 64 < (KK)) {                                                   \
        const int nb = (cur + 2 >= 3) ? cur - 1 : cur + 2;                    \
        GEMM_STAGE(AB, WB, LDA, LDB, k0 + 64, nb)                             \
      }                                                                       \
      f16x8 av[4], bv[4];                                                     \
      _Pragma("unroll")                                                       \
      for (int i = 0; i < 4; i++)                                             \
        av[i] = *(const f16x8*)&sA[cur * 4096 + (wm + i * 16 + lr) * 32 + q4 * 8]; \
      _Pragma("unroll")                                                       \
      for (int j = 0; j < 4; j++)                                             \
        bv[j] = *(const f16x8*)&sB[cur * 4096 + (wn + j * 16 + lr) * 32 + q4 * 8]; \
      _Pragma("unroll")                                                       \
      for (int i = 0; i < 4; i++)                                             \
        _Pragma("unroll")                                                     \
        for (int j = 0; j < 4; j++) acc[i][j] = mfma16(av[i], bv[j], acc[i][j]); \
      __builtin_amdgcn_sched_barrier(0x38F);                                  \
      cur = (cur == 2) ? 0 : cur + 1;                                         \
    }                                                                         \
  }

// ---------------------------------------------------------------------------
// LayerNorm: fp32 in -> f16 out, saves per-row mean and rstd (for router).
// ---------------------------------------------------------------------------
__global__ __launch_bounds__(256) void ln_kernel(
    const float* __restrict__ x, const float* __restrict__ g,
    const float* __restrict__ bt, f16* __restrict__ out,
    float* __restrict__ mout, float* __restrict__ rout)
{
  const int row = blockIdx.x;
  const float* xr = x + (long)row * 768;
  const int t = threadIdx.x;
  float v0 = xr[t], v1 = xr[t + 256], v2 = xr[t + 512];
  __shared__ float sb[8];
  float s = v0 + v1 + v2;
  #pragma unroll
  for (int o = 32; o > 0; o >>= 1) s += __shfl_xor(s, o, 64);
  const int w = t >> 6;
  if ((t & 63) == 0) sb[w] = s;
  __syncthreads();
  const float mean = (sb[0] + sb[1] + sb[2] + sb[3]) * (1.0f / 768.0f);
  const float d0 = v0 - mean, d1 = v1 - mean, d2 = v2 - mean;
  float q = d0 * d0 + d1 * d1 + d2 * d2;
  #pragma unroll
  for (int o = 32; o > 0; o >>= 1) q += __shfl_xor(q, o, 64);
  if ((t & 63) == 0) sb[4 + w] = q;
  __syncthreads();
  const float var = (sb[4] + sb[5] + sb[6] + sb[7]) * (1.0f / 768.0f);
  const float rstd = rsqrtf(var + 1e-5f);
  f16* orow = out + (long)row * 768;
  orow[t]       = (f16)(d0 * rstd * g[t]       + bt[t]);
  orow[t + 256] = (f16)(d1 * rstd * g[t + 256] + bt[t + 256]);
  orow[t + 512] = (f16)(d2 * rstd * g[t + 512] + bt[t + 512]);
  if (t == 0) { mout[row] = mean; rout[row] = rstd; }
}

// ---------------------------------------------------------------------------
// Fused transpose of all 6 weight matrices, fp32 [r][c] -> f16 [c][r].
// ---------------------------------------------------------------------------
struct TransArgs {
  const float* src[6];
  f16* dst[6];
  int rows[6], cols[6];
  int start[7];
};

__global__ __launch_bounds__(256) void transpose_all(TransArgs ta) {
  const int bid = blockIdx.x;
  int m = 0;
  #pragma unroll
  for (int i = 1; i < 6; i++) if (bid >= ta.start[i]) m = i;
  const int rows = ta.rows[m], cols = ta.cols[m];
  const int tilesC = cols >> 5;
  const int perB = (rows >> 5) * tilesC;
  int local = bid - ta.start[m];
  const int z = local / perB; local -= z * perB;
  const int tr = local / tilesC, tc = local - tr * tilesC;
  const float* inb = ta.src[m] + (long)z * rows * cols;
  f16* outb = ta.dst[m] + (long)z * rows * cols;
  const int c0 = tc * 32, r0 = tr * 32;
  __shared__ float tile[32][33];
  const int tx = threadIdx.x & 31, ty = threadIdx.x >> 5;
  #pragma unroll
  for (int i = 0; i < 32; i += 8)
    tile[ty + i][tx] = inb[(long)(r0 + ty + i) * cols + c0 + tx];
  __syncthreads();
  #pragma unroll
  for (int i = 0; i < 32; i += 8)
    outb[(long)(c0 + ty + i) * rows + r0 + tx] = (f16)tile[tx][ty + i];
}

// ---------------------------------------------------------------------------
// Generic GEMM: C[M,N] = A[M,K] @ W^T   (A f16 row-major, W f16 [N][K]).
// 128x128 tile, BK=32, 4 waves x 64x64. R8 double-buffered staging.
// ---------------------------------------------------------------------------
#define EPI_QKV     0
#define EPI_RESID   1

template <int EPI>
__global__ __launch_bounds__(256) void gemm_bt(
    const f16* __restrict__ A, int K, long strideA, int aShift,
    const f16* __restrict__ W, long strideW,
    const float* __restrict__ bias, int strideBias,
    const int* __restrict__ topkIdx,
    void* __restrict__ outv, long strideOut, int ldout,
    const float* __restrict__ resid)
{
  __shared__ f16 sA[2 * 128 * 32];
  __shared__ f16 sB[2 * 128 * 32];
  const int tid = threadIdx.x;
  const int pair = blockIdx.z;
  const int m0 = blockIdx.y * 128;
  const int n0 = blockIdx.x * 128;
  const f16* Ab = A + ((long)(pair >> aShift)) * strideA + (long)m0 * K;
  const int wsel = topkIdx ? topkIdx[pair] : pair;
  const f16* Wb = W + (long)wsel * strideW + (long)n0 * K;

  const int f = tid * 8;
  const int fr = f >> 5;
  const int fc = f & 31;
  const int lane = tid & 63, wid = tid >> 6;
  const int wm = (wid >> 1) * 64, wn = (wid & 1) * 64;
  const int lr = lane & 15, q4 = lane >> 4;

  f32x4 zero = {0.f, 0.f, 0.f, 0.f};
  f32x4 acc[4][4];
  #pragma unroll
  for (int i = 0; i < 4; i++)
    #pragma unroll
    for (int j = 0; j < 4; j++) acc[i][j] = zero;

  GEMM_CORE2(Ab, Wb, K, K, K);

  // Epilogue. C/D layout: col = lane&15, row = (lane>>4)*4 + reg.
  #pragma unroll
  for (int i = 0; i < 4; i++) {
    #pragma unroll
    for (int j = 0; j < 4; j++) {
      #pragma unroll
      for (int r = 0; r < 4; r++) {
        const int row = m0 + wm + i * 16 + q4 * 4 + r;
        const int col = n0 + wn + j * 16 + lr;
        float v = acc[i][j][r];
        if constexpr (EPI == EPI_QKV) {
          f16* qb = (f16*)outv;
          const int i3 = col / 768;
          const int rem = col - i3 * 768;
          const int hh = rem >> 6, dd = rem & 63;
          const int bb = row >> 9, ss = row & 511;
          const long bh = bb * 12 + hh;
          if (i3 == 0)      qb[(bh * 512 + ss) * 64 + dd] = (f16)v;           // Q
          else if (i3 == 1) qb[3145728 + (bh * 512 + ss) * 64 + dd] = (f16)v; // K
          else              qb[6291456 + (bh * 64 + dd) * 512 + ss] = (f16)v; // V^T
        } else {  // EPI_RESID
          float* ob = (float*)outv;
          v += bias[col];
          ob[(long)row * ldout + col] = resid[(long)row * ldout + col] + v;
        }
      }
    }
  }
}

// ---------------------------------------------------------------------------
// Merged FFN1: shared FFN1 (768 blocks) + expert FFN1 (1536 blocks), K=768.
// Distance-2 counted-vmcnt core; LDS-staged vectorized epilogue.
//   shared: shid[row][col] = gelu(hbuf@shw1t + shb1)
//   expert: hid[pair][row][col] = gelu(hbuf_b@ew1t[e] + eb1[e]) * w_k
// ---------------------------------------------------------------------------
__global__ __launch_bounds__(256) void gemm_ffn1(
    const f16* __restrict__ hbuf,
    const f16* __restrict__ shw1t, const float* __restrict__ shb1,
    const f16* __restrict__ ew1t,  const float* __restrict__ eb1,
    const int* __restrict__ topk,  const float* __restrict__ wslot,
    f16* __restrict__ shid, f16* __restrict__ hid)
{
  __shared__ f16 smem[3 * 4096 * 2];    // 48KB: 3-buf staging; epilogue scratch
  f16* sA = smem;
  f16* sB = smem + 3 * 4096;
  const int orig = blockIdx.x;          // 2304 = 8 XCDs x 288
  const int xcd = orig & 7, slot = orig >> 3;

  const int tid = threadIdx.x;
  const int f = tid * 8;
  const int fr = f >> 5, fc = f & 31;
  const int lane = tid & 63, wid = tid >> 6;
  const int wm = (wid >> 1) * 64, wn = (wid & 1) * 64;
  const int lr = lane & 15, q4 = lane >> 4;

  const f16* Ab;
  const f16* Wb;
  const float* bp;
  f16* outp;
  int ldo;
  float wscale;

  if (slot < 96) {                      // shared role: l in [0,768)
    const int l = xcd * 96 + slot;
    const int bx = l % 24, by = l / 24; // n-tile 0..23, m-tile 0..31
    const int n0 = bx * 128, m0 = by * 128;
    Ab = hbuf + (long)m0 * 768;
    Wb = shw1t + (long)n0 * 768;
    bp = shb1 + n0;
    outp = shid + (long)m0 * 3072 + n0;
    ldo = 3072;
    wscale = 1.f;
  } else {                              // expert role: l in [0,1536)
    const int l = xcd * 192 + (slot - 96);
    const int bx = l % 12;
    const int u = l / 12;
    const int by = u & 3, pair = u >> 2;
    const int wsel = topk[pair];
    const int n0 = bx * 128;
    const int m0g = (pair >> 2) * 512 + by * 128;   // global row in hbuf
    Ab = hbuf + (long)m0g * 768;
    Wb = ew1t + (long)wsel * (1536L * 768) + (long)n0 * 768;
    bp = eb1 + (long)wsel * 1536 + n0;
    outp = hid + (long)pair * (512L * 1536) + (long)(by * 128) * 1536 + n0;
    ldo = 1536;
    wscale = wslot[pair];
  }

  f32x4 zero = {0.f, 0.f, 0.f, 0.f};
  f32x4 acc[4][4];
  #pragma unroll
  for (int i = 0; i < 4; i++)
    #pragma unroll
    for (int j = 0; j < 4; j++) acc[i][j] = zero;

  GEMM_CORE3(Ab, Wb, 768, 768, 768);

  // LDS-staged vectorized epilogue: acc -> f16 scratch[128][128] -> 16B stores.
  __syncthreads();
  #pragma unroll
  for (int i = 0; i < 4; i++)
    #pragma unroll
    for (int j = 0; j < 4; j++)
      #pragma unroll
      for (int r = 0; r < 4; r++) {
        const int rr = wm + i * 16 + q4 * 4 + r;
        const int cc = wn + j * 16 + lr;
        float v = acc[i][j][r] + bp[cc];
        smem[rr * 128 + cc] = (f16)(gelu_fast(v) * wscale);
      }
  __syncthreads();
  {
    const int rsub = tid >> 4;          // 0..15
    const int cseg = (tid & 15) * 8;    // f16 col, 16B segments
    #pragma unroll
    for (int g = 0; g < 8; g++) {
      const int row = g * 16 + rsub;
      *(f16x8*)&outp[(long)row * ldo + cseg] =
          *(const f16x8*)&smem[row * 128 + cseg];
    }
  }
}

// ---------------------------------------------------------------------------
// Merged FFN2: shared FFN2 (192 blocks, K=3072) + expert FFN2 (768 blocks,
// K=1536) in one 960-block launch. R8 dbuf core; vectorized epilogues.
//   shared: dout[row][col] = x2 + shid@shw2t + shb2         (fp32, 2 passes)
//   expert: eo[pair][row][col] = hid@ew2t[e] + w_k*eb2[e]   (f16)
// ---------------------------------------------------------------------------
__global__ __launch_bounds__(256) void gemm_ffn2(
    const f16* __restrict__ shid, const f16* __restrict__ shw2t,
    const float* __restrict__ shb2, const float* __restrict__ x2,
    const f16* __restrict__ hid, const f16* __restrict__ ew2t,
    const float* __restrict__ eb2,
    const int* __restrict__ topk, const float* __restrict__ wslot,
    float* __restrict__ dout, f16* __restrict__ eo)
{
  __shared__ f16 smem[2 * 4096 * 2];    // 32KB: 2-buf staging; epilogue scratch
  f16* sA = smem;
  f16* sB = smem + 2 * 4096;
  const int orig = blockIdx.x;          // 960 = 8 XCDs x 120
  const int xcd = orig & 7, slot = orig >> 3;

  const int tid = threadIdx.x;
  const int f = tid * 8;
  const int fr = f >> 5, fc = f & 31;
  const int lane = tid & 63, wid = tid >> 6;
  const int wm = (wid >> 1) * 64, wn = (wid & 1) * 64;
  const int lr = lane & 15, q4 = lane >> 4;

  const bool shared_role = (slot < 24);
  const f16* Ab;
  const f16* Wb;
  int m0, n0, pair = 0, wsel = 0;

  if (shared_role) {                    // l in [0,192)
    const int l = xcd * 24 + slot;
    const int bx = l % 6, by = l / 6;   // n-tile 0..5, m-tile 0..31
    n0 = bx * 128; m0 = by * 128;
    Ab = shid + (long)m0 * 3072;
    Wb = shw2t + (long)n0 * 3072;
  } else {                              // l in [0,768)
    const int l = xcd * 96 + (slot - 24);
    const int bx = l % 6;
    const int u = l / 6;
    const int by = u & 3; pair = u >> 2;
    wsel = topk[pair];
    n0 = bx * 128; m0 = by * 128;       // m0 local within 512-row slot
    Ab = hid + (long)pair * (512L * 1536) + (long)m0 * 1536;
    Wb = ew2t + (long)wsel * (768L * 1536) + (long)n0 * 1536;
  }

  f32x4 zero = {0.f, 0.f, 0.f, 0.f};
  f32x4 acc[4][4];
  #pragma unroll
  for (int i = 0; i < 4; i++)
    #pragma unroll
    for (int j = 0; j < 4; j++) acc[i][j] = zero;

  if (shared_role) {
    GEMM_CORE2(Ab, Wb, 3072, 3072, 3072);
  } else {
    GEMM_CORE2(Ab, Wb, 1536, 1536, 1536);
  }

  __syncthreads();
  if (shared_role) {
    // fp32 output in two 64-row passes through 32KB scratch.
    float* sf = (float*)smem;           // 64 x 128 f32
    float* op = dout + (long)m0 * 768 + n0;
    const float* rp = x2 + (long)m0 * 768 + n0;
    const float* bp = shb2 + n0;
    #pragma unroll
    for (int p = 0; p < 2; p++) {
      if ((wid >> 1) == p) {
        #pragma unroll
        for (int i = 0; i < 4; i++)
          #pragma unroll
          for (int j = 0; j < 4; j++)
            #pragma unroll
            for (int r = 0; r < 4; r++)
              sf[(i * 16 + q4 * 4 + r) * 128 + wn + j * 16 + lr] = acc[i][j][r];
      }
      __syncthreads();
      #pragma unroll
      for (int g = 0; g < 8; g++) {
        const int rl = g * 8 + (tid >> 5);
        const int c4 = (tid & 31) * 4;
        const int grow = p * 64 + rl;
        f32x4 v = *(const f32x4*)&sf[rl * 128 + c4];
        const f32x4 rv = *(const f32x4*)&rp[(long)grow * 768 + c4];
        const f32x4 bv = *(const f32x4*)&bp[c4];
        v = v + rv + bv;
        *(f32x4*)&op[(long)grow * 768 + c4] = v;
      }
      __syncthreads();
    }
  } else {
    const float wscale = wslot[pair];
    const float* bp = eb2 + (long)wsel * 768 + n0;
    f16* op = eo + (long)pair * (512L * 768) + (long)m0 * 768 + n0;
    #pragma unroll
    for (int i = 0; i < 4; i++)
      #pragma unroll
      for (int j = 0; j < 4; j++)
        #pragma unroll
        for (int r = 0; r < 4; r++) {
          const int rr = wm + i * 16 + q4 * 4 + r;
          const int cc = wn + j * 16 + lr;
          smem[rr * 128 + cc] = (f16)(acc[i][j][r] + wscale * bp[cc]);
        }
    __syncthreads();
    const int rsub = tid >> 4;
    const int cseg = (tid & 15) * 8;
    #pragma unroll
    for (int g = 0; g < 8; g++) {
      const int row = g * 16 + rsub;
      *(f16x8*)&op[(long)row * 768 + cseg] =
          *(const f16x8*)&smem[row * 128 + cseg];
    }
  }
}

// ---------------------------------------------------------------------------
// Fused attention per (b*h, q-tile of 64). P lives in LDS (XOR-swizzled);
// each wave touches only its own 16 q-rows -> no barrier needed.
// ---------------------------------------------------------------------------
__device__ __forceinline__ int pswz(int row, int col) {
  return row * 512 + (col ^ ((row & 7) << 3));
}

__global__ __launch_bounds__(256) void attn_kernel(
    const f16* __restrict__ Q, const f16* __restrict__ Kt,
    const f16* __restrict__ Vt, f16* __restrict__ AO)
{
  __shared__ f16 Ps[64 * 512];
  const int bh = blockIdx.x;
  const int qt = blockIdx.y;
  const int t = threadIdx.x;
  const int lane = t & 63, w = t >> 6;
  const int lr = lane & 15, q4 = lane >> 4;
  const int r0 = qt * 64 + w * 16;
  const int lrow0 = w * 16;
  const f16* Qh = Q + (long)bh * 512 * 64;
  const f16* Kh = Kt + (long)bh * 512 * 64;

  f32x4 zero = {0.f, 0.f, 0.f, 0.f};
  f32x4 acc[32];
  #pragma unroll
  for (int i = 0; i < 32; i++) acc[i] = zero;

  #pragma unroll
  for (int kk = 0; kk < 2; kk++) {
    f16x8 a = *(const f16x8*)&Qh[(r0 + lr) * 64 + kk * 32 + q4 * 8];
    #pragma unroll
    for (int nt = 0; nt < 32; nt++) {
      f16x8 b = *(const f16x8*)&Kh[(nt * 16 + lr) * 64 + kk * 32 + q4 * 8];
      acc[nt] = mfma16(a, b, acc[nt]);
    }
  }

  const float cscale = 0.125f * 1.44269504089f;
  #pragma unroll
  for (int r = 0; r < 4; r++) {
    float m = -1e30f;
    #pragma unroll
    for (int nt = 0; nt < 32; nt++) m = fmaxf(m, acc[nt][r]);
    #pragma unroll
    for (int o = 1; o < 16; o <<= 1) m = fmaxf(m, __shfl_xor(m, o, 64));
    float s = 0.f;
    #pragma unroll
    for (int nt = 0; nt < 32; nt++) {
      float e = exp2f((acc[nt][r] - m) * cscale);
      acc[nt][r] = e; s += e;
    }
    #pragma unroll
    for (int o = 1; o < 16; o <<= 1) s += __shfl_xor(s, o, 64);
    const float inv = 1.f / s;
    const int lrow = lrow0 + q4 * 4 + r;
    #pragma unroll
    for (int nt = 0; nt < 32; nt++)
      Ps[pswz(lrow, nt * 16 + lr)] = (f16)(acc[nt][r] * inv);
  }

  const f16* Vh = Vt + (long)bh * 64 * 512;
  f32x4 o4[4];
  #pragma unroll
  for (int i = 0; i < 4; i++) o4[i] = zero;
  #pragma unroll
  for (int kk = 0; kk < 16; kk++) {
    f16x8 a = *(const f16x8*)&Ps[pswz(lrow0 + lr, kk * 32 + q4 * 8)];
    #pragma unroll
    for (int nt = 0; nt < 4; nt++) {
      f16x8 b = *(const f16x8*)&Vh[(nt * 16 + lr) * 512 + kk * 32 + q4 * 8];
      o4[nt] = mfma16(a, b, o4[nt]);
    }
  }
  const int b_ = bh / 12, h_ = bh - b_ * 12;
  #pragma unroll
  for (int nt = 0; nt < 4; nt++)
    #pragma unroll
    for (int r = 0; r < 4; r++) {
      const int rowg = r0 + q4 * 4 + r;
      AO[((long)(b_ * 512 + rowg)) * 768 + h_ * 64 + nt * 16 + lr] = (f16)o4[nt][r];
    }
}

// ---------------------------------------------------------------------------
// Router stage 1: partial sums of (x-m)*r over 32-row chunks. part[b][c][768].
// ---------------------------------------------------------------------------
__global__ __launch_bounds__(256) void router_reduce(
    const float* __restrict__ x2, const float* __restrict__ lnm,
    const float* __restrict__ lnr, float* __restrict__ part)
{
  const int c = blockIdx.x, b = blockIdx.y, t = threadIdx.x;
  float a0 = 0.f, a1 = 0.f, a2 = 0.f;
  #pragma unroll 4
  for (int s = 0; s < 32; s++) {
    const long base = (long)b * 512 + c * 32 + s;
    const float m = lnm[base], r = lnr[base];
    const float* xr = x2 + base * 768;
    a0 += (xr[t] - m) * r;
    a1 += (xr[t + 256] - m) * r;
    a2 += (xr[t + 512] - m) * r;
  }
  float* pr = part + ((long)b * 16 + c) * 768;
  pr[t] = a0; pr[t + 256] = a1; pr[t + 512] = a2;
}

// ---------------------------------------------------------------------------
// Router stage 2: fold partials -> seq_repr (fp32, global).
// ---------------------------------------------------------------------------
__global__ __launch_bounds__(256) void router_seq(
    const float* __restrict__ part, const float* __restrict__ g2,
    const float* __restrict__ b2ln, float* __restrict__ seqg)
{
  const int b = blockIdx.x, t = threadIdx.x;
  const float* pb = part + (long)b * 16 * 768;
  #pragma unroll
  for (int i = 0; i < 3; i++) {
    const int j = t + 256 * i;
    float a = 0.f;
    #pragma unroll
    for (int c = 0; c < 16; c++) a += pb[c * 768 + j];
    seqg[b * 768 + j] = a * (1.f / 512.f) * g2[j] + b2ln[j];
  }
}

// ---------------------------------------------------------------------------
// Router stage 3: MLP1 partials over 48-deep d-slices.
// ---------------------------------------------------------------------------
__global__ __launch_bounds__(256) void router_mlp1(
    const float* __restrict__ seqg, const float* __restrict__ rw1,
    float* __restrict__ pmlp)
{
  const int c = blockIdx.x, b = blockIdx.y, t = threadIdx.x;
  const float* sq = seqg + b * 768 + c * 48;
  float a0 = 0.f, a1 = 0.f, a2 = 0.f;
  #pragma unroll 8
  for (int d = 0; d < 48; d++) {
    const float s = sq[d];
    const float* wr = rw1 + (long)(c * 48 + d) * 768;
    a0 += s * wr[t];
    a1 += s * wr[t + 256];
    a2 += s * wr[t + 512];
  }
  float* pr = pmlp + ((long)b * 16 + c) * 768;
  pr[t] = a0; pr[t + 256] = a1; pr[t + 512] = a2;
}

// ---------------------------------------------------------------------------
// Router stage 4: fold MLP1 partials + bias + gelu (exact fp32) -> g1g.
// ---------------------------------------------------------------------------
__global__ __launch_bounds__(256) void router_fold(
    const float* __restrict__ pmlp, const float* __restrict__ rb1,
    float* __restrict__ g1g)
{
  const int b = blockIdx.x, t = threadIdx.x;
  const float* pb = pmlp + (long)b * 16 * 768;
  #pragma unroll
  for (int i = 0; i < 3; i++) {
    const int j = t + 256 * i;
    float a = rb1[j];
    #pragma unroll
    for (int c = 0; c < 16; c++) a += pb[c * 768 + j];
    g1g[b * 768 + j] = 0.5f * a * (1.0f + erff(a * 0.70710678118654752f));
  }
}

// ---------------------------------------------------------------------------
// Router stage 5: logits; softmax; top4; renorm (fp32 exact selection).
// ---------------------------------------------------------------------------
__global__ __launch_bounds__(256) void router_top(
    const float* __restrict__ g1g, const float* __restrict__ rw2,
    const float* __restrict__ rb2, float* __restrict__ wslot,
    int* __restrict__ topkIdx)
{
  __shared__ float lg[14];
  const int b = blockIdx.x, t = threadIdx.x;
  const int e = t >> 4, sub = t & 15;
  if (e < 14) {
    float a = 0.f;
    #pragma unroll
    for (int i = 0; i < 48; i++) {
      const int d = sub + 16 * i;
      a += g1g[b * 768 + d] * rw2[d * 14 + e];
    }
    #pragma unroll
    for (int o = 1; o < 16; o <<= 1) a += __shfl_xor(a, o, 64);
    if (sub == 0) lg[e] = a + rb2[e];
  }
  __syncthreads();
  if (t == 0) {
    float mx = -1e30f;
    for (int ee = 0; ee < 14; ee++) mx = fmaxf(mx, lg[ee]);
    float p[14], s = 0.f;
    for (int ee = 0; ee < 14; ee++) { p[ee] = expf(lg[ee] - mx); s += p[ee]; }
    for (int ee = 0; ee < 14; ee++) p[ee] /= s;
    int idx[4]; float val[4]; bool used[14];
    for (int ee = 0; ee < 14; ee++) used[ee] = false;
    for (int k = 0; k < 4; k++) {
      int best = -1; float bv = -1.f;
      for (int ee = 0; ee < 14; ee++)
        if (!used[ee] && p[ee] > bv) { bv = p[ee]; best = ee; }
      used[best] = true; idx[k] = best; val[k] = bv;
    }
    const float m2 = val[0];
    float ss = 0.f, e4[4];
    for (int k = 0; k < 4; k++) { e4[k] = expf(val[k] - m2); ss += e4[k]; }
    for (int k = 0; k < 4; k++) {
      wslot[b * 4 + k] = e4[k] / ss;
      topkIdx[b * 4 + k] = idx[k];
    }
  }
}

// ---------------------------------------------------------------------------
// Final combine (vectorized): out += eo0+eo1+eo2+eo3, 4 elems/thread.
// ---------------------------------------------------------------------------
__global__ __launch_bounds__(256) void combine_kernel(
    const f16* __restrict__ eo, float* __restrict__ out)
{
  const long i4 = ((long)blockIdx.x * 256 + threadIdx.x) * 4;
  const long b = i4 / (512L * 768);
  const long loc = i4 - b * (512L * 768);
  const f16* e0 = eo + b * 4 * (512L * 768) + loc;
  f32x4 v = *(const f32x4*)&out[i4];
  #pragma unroll
  for (int s = 0; s < 4; s++) {
    const f16x4 ev = *(const f16x4*)&e0[s * (512L * 768)];
    v.x += (float)ev[0];
    v.y += (float)ev[1];
    v.z += (float)ev[2];
    v.w += (float)ev[3];
  }
  *(f32x4*)&out[i4] = v;
}

// ---------------------------------------------------------------------------
// Workspace layout (bytes). Weights persistent; activations alias.
// Total ~191.5 MB.
// ---------------------------------------------------------------------------
static const long OFF_X2    = 0L;                       // 12582912
static const long OFF_LNM   = 12582912L;
static const long OFF_LNR   = OFF_LNM + 16384L;
static const long OFF_WSLOT = OFF_LNR + 16384L;
static const long OFF_TOPK  = OFF_WSLOT + 256L;
static const long OFF_PART  = OFF_TOPK + 256L;          // 393216
static const long OFF_SEQG  = OFF_PART + 393216L;
static const long OFF_PMLP  = OFF_SEQG + 24576L;
static const long OFF_G1G   = OFF_PMLP + 393216L;       // ends 13451776
// persistent transposed weights
static const long W_QKVWT  = 13631488L;                 // 3538944
static const long W_PROJWT = W_QKVWT + 3538944L;        // 1179648
static const long W_EW1T   = W_PROJWT + 1179648L;       // 33030144
static const long W_EW2T   = W_EW1T + 33030144L;        // 33030144
static const long W_SHW1T  = W_EW2T + 33030144L;        // 4718592
static const long W_SHW2T  = W_SHW1T + 4718592L;        // 4718592 -> 93847552
// activation region (phase A aliases phase B)
static const long OFF_ACT  = 93847552L;
static const long A_H1     = OFF_ACT;                   // 6291456
static const long A_Q      = OFF_ACT + 6291456L;        // 3 x 6291456
static const long A_AO     = A_Q + 18874368L;           // 6291456
static const long B_H      = OFF_ACT;                   // 6291456
static const long B_HID    = OFF_ACT + 6291456L;        // 50331648
static const long B_SHID   = B_HID + 50331648L;         // 25165824
static const long B_EO     = B_SHID + 25165824L;        // 25165824 -> ends 200802304

extern "C" void kernel_launch(void* const* d_in, const int* in_sizes, int n_in,
                              void* d_out, int out_size, void* d_ws, size_t ws_size,
                              hipStream_t stream) {
  const float* x     = (const float*)d_in[0];
  const float* ln1g  = (const float*)d_in[1];
  const float* ln1b  = (const float*)d_in[2];
  const float* qkvw  = (const float*)d_in[3];
  const float* projw = (const float*)d_in[4];
  const float* projb = (const float*)d_in[5];
  const float* ln2g  = (const float*)d_in[6];
  const float* ln2b  = (const float*)d_in[7];
  const float* rw1   = (const float*)d_in[8];
  const float* rb1   = (const float*)d_in[9];
  const float* rw2   = (const float*)d_in[10];
  const float* rb2   = (const float*)d_in[11];
  const float* ew1   = (const float*)d_in[12];
  const float* eb1   = (const float*)d_in[13];
  const float* ew2   = (const float*)d_in[14];
  const float* eb2   = (const float*)d_in[15];
  const float* shw1  = (const float*)d_in[16];
  const float* shb1  = (const float*)d_in[17];
  const float* shw2  = (const float*)d_in[18];
  const float* shb2  = (const float*)d_in[19];

  char* ws = (char*)d_ws;
  float* x2    = (float*)(ws + OFF_X2);
  float* lnm   = (float*)(ws + OFF_LNM);
  float* lnr   = (float*)(ws + OFF_LNR);
  float* wslot = (float*)(ws + OFF_WSLOT);
  int*   topk  = (int*)(ws + OFF_TOPK);
  float* part  = (float*)(ws + OFF_PART);
  float* seqg  = (float*)(ws + OFF_SEQG);
  float* pmlp  = (float*)(ws + OFF_PMLP);
  float* g1g   = (float*)(ws + OFF_G1G);
  f16* qkvwt  = (f16*)(ws + W_QKVWT);
  f16* projwt = (f16*)(ws + W_PROJWT);
  f16* ew1t   = (f16*)(ws + W_EW1T);
  f16* ew2t   = (f16*)(ws + W_EW2T);
  f16* shw1t  = (f16*)(ws + W_SHW1T);
  f16* shw2t  = (f16*)(ws + W_SHW2T);
  f16* h1     = (f16*)(ws + A_H1);
  f16* Qb     = (f16*)(ws + A_Q);
  f16* aob    = (f16*)(ws + A_AO);
  f16* hbuf   = (f16*)(ws + B_H);
  f16* hid    = (f16*)(ws + B_HID);
  f16* shid   = (f16*)(ws + B_SHID);
  f16* eo     = (f16*)(ws + B_EO);

  // ---- all weight transposes in one launch ----
  TransArgs ta;
  ta.src[0] = qkvw;  ta.dst[0] = qkvwt;  ta.rows[0] = 768;  ta.cols[0] = 2304;
  ta.src[1] = projw; ta.dst[1] = projwt; ta.rows[1] = 768;  ta.cols[1] = 768;
  ta.src[2] = ew1;   ta.dst[2] = ew1t;   ta.rows[2] = 768;  ta.cols[2] = 1536;
  ta.src[3] = ew2;   ta.dst[3] = ew2t;   ta.rows[3] = 1536; ta.cols[3] = 768;
  ta.src[4] = shw1;  ta.dst[4] = shw1t;  ta.rows[4] = 768;  ta.cols[4] = 3072;
  ta.src[5] = shw2;  ta.dst[5] = shw2t;  ta.rows[5] = 3072; ta.cols[5] = 768;
  ta.start[0] = 0;     ta.start[1] = 1728;  ta.start[2] = 2304;
  ta.start[3] = 18432; ta.start[4] = 34560; ta.start[5] = 36864;
  ta.start[6] = 39168;
  transpose_all<<<39168, 256, 0, stream>>>(ta);

  // ---- Phase A: attention ----
  ln_kernel<<<4096, 256, 0, stream>>>(x, ln1g, ln1b, h1, lnm, lnr);
  gemm_bt<EPI_QKV><<<dim3(18, 32, 1), 256, 0, stream>>>(
      h1, 768, 0, 0, qkvwt, 0, nullptr, 0, nullptr, (void*)Qb, 0, 0, nullptr);
  attn_kernel<<<dim3(96, 8, 1), 256, 0, stream>>>(Qb, Qb + 3145728, Qb + 6291456, aob);
  gemm_bt<EPI_RESID><<<dim3(6, 32, 1), 256, 0, stream>>>(
      aob, 768, 0, 0, projwt, 0, projb, 0, nullptr, (void*)x2, 0, 768, x);

  // ---- Phase B: MoE ----
  ln_kernel<<<4096, 256, 0, stream>>>(x2, ln2g, ln2b, hbuf, lnm, lnr);
  router_reduce<<<dim3(16, 8, 1), 256, 0, stream>>>(x2, lnm, lnr, part);
  router_seq<<<8, 256, 0, stream>>>(part, ln2g, ln2b, seqg);
  router_mlp1<<<dim3(16, 8, 1), 256, 0, stream>>>(seqg, rw1, pmlp);
  router_fold<<<8, 256, 0, stream>>>(pmlp, rb1, g1g);
  router_top<<<8, 256, 0, stream>>>(g1g, rw2, rb2, wslot, topk);
  // merged FFN1: shared (768 blocks) + expert (1536 blocks), K=768 uniform
  gemm_ffn1<<<2304, 256, 0, stream>>>(hbuf, shw1t, shb1, ew1t, eb1,
                                      topk, wslot, shid, hid);
  // merged FFN2: shared (192 blocks, K=3072) + expert (768 blocks, K=1536)
  gemm_ffn2<<<960, 256, 0, stream>>>(shid, shw2t, shb2, x2, hid, ew2t, eb2,
                                     topk, wslot, (float*)d_out, eo);
  combine_kernel<<<3072, 256, 0, stream>>>(eo, (float*)d_out);
}

// Round 6
// 568.218 us; speedup vs baseline: 1.0475x; 1.0275x over previous
//
#include <hip/hip_runtime.h>
#include <hip/hip_bf16.h>

// ---------------------------------------------------------------------------
// MoE transformer block, MI355X gfx950.
// B=8 S=512 D=768 H=12 dh=64 E=14 K=4 HID=1536 SH=3072
// R11: (1) ffn1 -> distance-3 pipeline (4 LDS buffers, 64KB, vmcnt(8)
//      steady state). Tail corrected: vmcnt(8)/(4)/(0) for the last three
//      steps (flat vmcnt(8) would not guarantee stage-k completion once
//      fewer than 2 stages remain in flight). Expert weights (33MB) are
//      HBM-resident -> ~900cy latency needs ~3 windows of cover.
//      (2) ffn2 -> R10-validated distance-2 core (R9's ffn2 regression was
//      the full-pin variant; the 0x38F-relaxed one measured 108->98 on ffn1).
//      (3) qkv/proj -> distance-2 core too.
//      Keeps: merged FFN1/FFN2 grids, XCD grouping, w_k in FFN1 epilogue,
//      vectorized LDS-staged epilogues, fast GELU, LDS attn, fused transpose.
// ---------------------------------------------------------------------------

typedef _Float16 f16x8 __attribute__((ext_vector_type(8)));
typedef _Float16 f16x4 __attribute__((ext_vector_type(4)));
typedef float f32x4 __attribute__((ext_vector_type(4)));
typedef _Float16 f16;

// tanh-form GELU: one v_exp_f32; |diff vs erf-gelu| <= ~3e-3.
__device__ __forceinline__ float gelu_fast(float x) {
  const float k2l2e = 2.f * 0.7978845608028654f * 1.4426950408889634f;
  float u = (x + 0.044715f * x * x * x) * k2l2e;
  float t = exp2f(u);
  return x * (1.f - 1.f / (t + 1.f));
}

__device__ __forceinline__ f32x4 mfma16(f16x8 a, f16x8 b, f32x4 c) {
  return __builtin_amdgcn_mfma_f32_16x16x32_f16(a, b, c, 0, 0, 0);
}

// async global->LDS, 16B per lane; LDS dst must be wave-uniform base + lane*16
#define ASYNC_CP16(g, l)                                            \
  __builtin_amdgcn_global_load_lds(                                 \
      (const __attribute__((address_space(1))) void*)(g),           \
      (__attribute__((address_space(3))) void*)(l), 16, 0, 0)

// Stage one 128x32 A-tile and B-tile k-slice into LDS buffer `buf` (4 loads).
#define GEMM_STAGE(AB, WB, LDA, LDB, koff, buf)                               \
  ASYNC_CP16(&(AB)[(long)fr * (LDA) + (koff) + fc],        &sA[(buf) * 4096 + f]);        \
  ASYNC_CP16(&(AB)[(long)(fr + 64) * (LDA) + (koff) + fc], &sA[(buf) * 4096 + f + 2048]); \
  ASYNC_CP16(&(WB)[(long)fr * (LDB) + (koff) + fc],        &sB[(buf) * 4096 + f]);        \
  ASYNC_CP16(&(WB)[(long)(fr + 64) * (LDB) + (koff) + fc], &sB[(buf) * 4096 + f + 2048]);

// ds_read current buffer + 16 MFMAs (shared tail of every core).
#define GEMM_COMPUTE(bufidx)                                                  \
  {                                                                           \
    f16x8 av[4], bv[4];                                                       \
    _Pragma("unroll")                                                         \
    for (int i = 0; i < 4; i++)                                               \
      av[i] = *(const f16x8*)&sA[(bufidx) * 4096 + (wm + i * 16 + lr) * 32 + q4 * 8]; \
    _Pragma("unroll")                                                         \
    for (int j = 0; j < 4; j++)                                               \
      bv[j] = *(const f16x8*)&sB[(bufidx) * 4096 + (wn + j * 16 + lr) * 32 + q4 * 8]; \
    _Pragma("unroll")                                                         \
    for (int i = 0; i < 4; i++)                                               \
      _Pragma("unroll")                                                       \
      for (int j = 0; j < 4; j++) acc[i][j] = mfma16(av[i], bv[j], acc[i][j]); \
  }

// Distance-2 pipelined core (3 buffers, counted vmcnt). R10-validated on
// ffn1 (108->98us, VALUBusy 49%). Per step k: vmcnt(4) -> s_barrier ->
// sched_barrier(0) [pins ds_reads below barrier] -> stage k+2 into (k-1)%3
// -> ds_read k%3 -> MFMA -> sched_barrier(0x38F) [only VMEM blocked from
// crossing: keeps vmcnt counting exact, VALU/MFMA/DS free to schedule].
// Overwrite safety: all waves' step-(k-1) ds_reads retire before barrier k.
#define GEMM_CORE3(AB, WB, LDA, LDB, KK)                                      \
  {                                                                           \
    GEMM_STAGE(AB, WB, LDA, LDB, 0, 0)                                        \
    GEMM_STAGE(AB, WB, LDA, LDB, 32, 1)                                       \
    int cur = 0;                                                              \
    for (int k0 = 0; k0 < (KK); k0 += 32) {                                   \
      if (k0 + 32 < (KK)) {                                                   \
        asm volatile("s_waitcnt vmcnt(4)" ::: "memory");                      \
      } else {                                                                \
        asm volatile("s_waitcnt vmcnt(0)" ::: "memory");                      \
      }                                                                       \
      __builtin_amdgcn_s_barrier();                                           \
      __builtin_amdgcn_sched_barrier(0);                                      \
      if (k0 + 64 < (KK)) {                                                   \
        const int nb = (cur + 2 >= 3) ? cur - 1 : cur + 2;                    \
        GEMM_STAGE(AB, WB, LDA, LDB, k0 + 64, nb)                             \
      }                                                                       \
      GEMM_COMPUTE(cur)                                                       \
      __builtin_amdgcn_sched_barrier(0x38F);                                  \
      cur = (cur == 2) ? 0 : cur + 1;                                         \
    }                                                                         \
  }

// Distance-3 pipelined core (4 buffers, vmcnt(8) steady state). Tail waits
// step down 8 -> 4 -> 0: at step k the guaranteed-complete stage is k only
// when (outstanding - N) <= 4*(stages ahead); with 2 stages ahead use 8,
// with 1 use 4, last step 0. Stage k+3 overwrites buf (k-1)&3 after
// barrier k (same safety argument as distance-2).
#define GEMM_CORE4(AB, WB, LDA, LDB, KK)                                      \
  {                                                                           \
    GEMM_STAGE(AB, WB, LDA, LDB, 0, 0)                                        \
    GEMM_STAGE(AB, WB, LDA, LDB, 32, 1)                                       \
    GEMM_STAGE(AB, WB, LDA, LDB, 64, 2)                                       \
    int cur = 0;                                                              \
    for (int k0 = 0; k0 < (KK); k0 += 32) {                                   \
      if (k0 + 64 < (KK)) {                                                   \
        asm volatile("s_waitcnt vmcnt(8)" ::: "memory");                      \
      } else if (k0 + 32 < (KK)) {                                            \
        asm volatile("s_waitcnt vmcnt(4)" ::: "memory");                      \
      } else {                                                                \
        asm volatile("s_waitcnt vmcnt(0)" ::: "memory");                      \
      }                                                                       \
      __builtin_amdgcn_s_barrier();                                           \
      __builtin_amdgcn_sched_barrier(0);                                      \
      if (k0 + 96 < (KK)) {                                                   \
        const int nb = (cur + 3) & 3;                                         \
        GEMM_STAGE(AB, WB, LDA, LDB, k0 + 96, nb)                             \
      }                                                                       \
      GEMM_COMPUTE(cur)                                                       \
      __builtin_amdgcn_sched_barrier(0x38F);                                  \
      cur = (cur + 1) & 3;                                                    \
    }                                                                         \
  }

// ---------------------------------------------------------------------------
// LayerNorm: fp32 in -> f16 out, saves per-row mean and rstd (for router).
// ---------------------------------------------------------------------------
__global__ __launch_bounds__(256) void ln_kernel(
    const float* __restrict__ x, const float* __restrict__ g,
    const float* __restrict__ bt, f16* __restrict__ out,
    float* __restrict__ mout, float* __restrict__ rout)
{
  const int row = blockIdx.x;
  const float* xr = x + (long)row * 768;
  const int t = threadIdx.x;
  float v0 = xr[t], v1 = xr[t + 256], v2 = xr[t + 512];
  __shared__ float sb[8];
  float s = v0 + v1 + v2;
  #pragma unroll
  for (int o = 32; o > 0; o >>= 1) s += __shfl_xor(s, o, 64);
  const int w = t >> 6;
  if ((t & 63) == 0) sb[w] = s;
  __syncthreads();
  const float mean = (sb[0] + sb[1] + sb[2] + sb[3]) * (1.0f / 768.0f);
  const float d0 = v0 - mean, d1 = v1 - mean, d2 = v2 - mean;
  float q = d0 * d0 + d1 * d1 + d2 * d2;
  #pragma unroll
  for (int o = 32; o > 0; o >>= 1) q += __shfl_xor(q, o, 64);
  if ((t & 63) == 0) sb[4 + w] = q;
  __syncthreads();
  const float var = (sb[4] + sb[5] + sb[6] + sb[7]) * (1.0f / 768.0f);
  const float rstd = rsqrtf(var + 1e-5f);
  f16* orow = out + (long)row * 768;
  orow[t]       = (f16)(d0 * rstd * g[t]       + bt[t]);
  orow[t + 256] = (f16)(d1 * rstd * g[t + 256] + bt[t + 256]);
  orow[t + 512] = (f16)(d2 * rstd * g[t + 512] + bt[t + 512]);
  if (t == 0) { mout[row] = mean; rout[row] = rstd; }
}

// ---------------------------------------------------------------------------
// Fused transpose of all 6 weight matrices, fp32 [r][c] -> f16 [c][r].
// ---------------------------------------------------------------------------
struct TransArgs {
  const float* src[6];
  f16* dst[6];
  int rows[6], cols[6];
  int start[7];
};

__global__ __launch_bounds__(256) void transpose_all(TransArgs ta) {
  const int bid = blockIdx.x;
  int m = 0;
  #pragma unroll
  for (int i = 1; i < 6; i++) if (bid >= ta.start[i]) m = i;
  const int rows = ta.rows[m], cols = ta.cols[m];
  const int tilesC = cols >> 5;
  const int perB = (rows >> 5) * tilesC;
  int local = bid - ta.start[m];
  const int z = local / perB; local -= z * perB;
  const int tr = local / tilesC, tc = local - tr * tilesC;
  const float* inb = ta.src[m] + (long)z * rows * cols;
  f16* outb = ta.dst[m] + (long)z * rows * cols;
  const int c0 = tc * 32, r0 = tr * 32;
  __shared__ float tile[32][33];
  const int tx = threadIdx.x & 31, ty = threadIdx.x >> 5;
  #pragma unroll
  for (int i = 0; i < 32; i += 8)
    tile[ty + i][tx] = inb[(long)(r0 + ty + i) * cols + c0 + tx];
  __syncthreads();
  #pragma unroll
  for (int i = 0; i < 32; i += 8)
    outb[(long)(c0 + ty + i) * rows + r0 + tx] = (f16)tile[tx][ty + i];
}

// ---------------------------------------------------------------------------
// Generic GEMM: C[M,N] = A[M,K] @ W^T   (A f16 row-major, W f16 [N][K]).
// 128x128 tile, BK=32, 4 waves x 64x64. Distance-2 pipelined staging.
// ---------------------------------------------------------------------------
#define EPI_QKV     0
#define EPI_RESID   1

template <int EPI>
__global__ __launch_bounds__(256) void gemm_bt(
    const f16* __restrict__ A, int K, long strideA, int aShift,
    const f16* __restrict__ W, long strideW,
    const float* __restrict__ bias, int strideBias,
    const int* __restrict__ topkIdx,
    void* __restrict__ outv, long strideOut, int ldout,
    const float* __restrict__ resid)
{
  __shared__ f16 sA[3 * 128 * 32];
  __shared__ f16 sB[3 * 128 * 32];
  const int tid = threadIdx.x;
  const int pair = blockIdx.z;
  const int m0 = blockIdx.y * 128;
  const int n0 = blockIdx.x * 128;
  const f16* Ab = A + ((long)(pair >> aShift)) * strideA + (long)m0 * K;
  const int wsel = topkIdx ? topkIdx[pair] : pair;
  const f16* Wb = W + (long)wsel * strideW + (long)n0 * K;

  const int f = tid * 8;
  const int fr = f >> 5;
  const int fc = f & 31;
  const int lane = tid & 63, wid = tid >> 6;
  const int wm = (wid >> 1) * 64, wn = (wid & 1) * 64;
  const int lr = lane & 15, q4 = lane >> 4;

  f32x4 zero = {0.f, 0.f, 0.f, 0.f};
  f32x4 acc[4][4];
  #pragma unroll
  for (int i = 0; i < 4; i++)
    #pragma unroll
    for (int j = 0; j < 4; j++) acc[i][j] = zero;

  GEMM_CORE3(Ab, Wb, K, K, K);

  // Epilogue. C/D layout: col = lane&15, row = (lane>>4)*4 + reg.
  #pragma unroll
  for (int i = 0; i < 4; i++) {
    #pragma unroll
    for (int j = 0; j < 4; j++) {
      #pragma unroll
      for (int r = 0; r < 4; r++) {
        const int row = m0 + wm + i * 16 + q4 * 4 + r;
        const int col = n0 + wn + j * 16 + lr;
        float v = acc[i][j][r];
        if constexpr (EPI == EPI_QKV) {
          f16* qb = (f16*)outv;
          const int i3 = col / 768;
          const int rem = col - i3 * 768;
          const int hh = rem >> 6, dd = rem & 63;
          const int bb = row >> 9, ss = row & 511;
          const long bh = bb * 12 + hh;
          if (i3 == 0)      qb[(bh * 512 + ss) * 64 + dd] = (f16)v;           // Q
          else if (i3 == 1) qb[3145728 + (bh * 512 + ss) * 64 + dd] = (f16)v; // K
          else              qb[6291456 + (bh * 64 + dd) * 512 + ss] = (f16)v; // V^T
        } else {  // EPI_RESID
          float* ob = (float*)outv;
          v += bias[col];
          ob[(long)row * ldout + col] = resid[(long)row * ldout + col] + v;
        }
      }
    }
  }
}

// ---------------------------------------------------------------------------
// Merged FFN1: shared FFN1 (768 blocks) + expert FFN1 (1536 blocks), K=768.
// Distance-3 counted-vmcnt core; LDS-staged vectorized epilogue.
//   shared: shid[row][col] = gelu(hbuf@shw1t + shb1)
//   expert: hid[pair][row][col] = gelu(hbuf_b@ew1t[e] + eb1[e]) * w_k
// ---------------------------------------------------------------------------
__global__ __launch_bounds__(256) void gemm_ffn1(
    const f16* __restrict__ hbuf,
    const f16* __restrict__ shw1t, const float* __restrict__ shb1,
    const f16* __restrict__ ew1t,  const float* __restrict__ eb1,
    const int* __restrict__ topk,  const float* __restrict__ wslot,
    f16* __restrict__ shid, f16* __restrict__ hid)
{
  __shared__ f16 smem[4 * 4096 * 2];    // 64KB: 4-buf staging; epilogue scratch
  f16* sA = smem;
  f16* sB = smem + 4 * 4096;
  const int orig = blockIdx.x;          // 2304 = 8 XCDs x 288
  const int xcd = orig & 7, slot = orig >> 3;

  const int tid = threadIdx.x;
  const int f = tid * 8;
  const int fr = f >> 5, fc = f & 31;
  const int lane = tid & 63, wid = tid >> 6;
  const int wm = (wid >> 1) * 64, wn = (wid & 1) * 64;
  const int lr = lane & 15, q4 = lane >> 4;

  const f16* Ab;
  const f16* Wb;
  const float* bp;
  f16* outp;
  int ldo;
  float wscale;

  if (slot < 96) {                      // shared role: l in [0,768)
    const int l = xcd * 96 + slot;
    const int bx = l % 24, by = l / 24; // n-tile 0..23, m-tile 0..31
    const int n0 = bx * 128, m0 = by * 128;
    Ab = hbuf + (long)m0 * 768;
    Wb = shw1t + (long)n0 * 768;
    bp = shb1 + n0;
    outp = shid + (long)m0 * 3072 + n0;
    ldo = 3072;
    wscale = 1.f;
  } else {                              // expert role: l in [0,1536)
    const int l = xcd * 192 + (slot - 96);
    const int bx = l % 12;
    const int u = l / 12;
    const int by = u & 3, pair = u >> 2;
    const int wsel = topk[pair];
    const int n0 = bx * 128;
    const int m0g = (pair >> 2) * 512 + by * 128;   // global row in hbuf
    Ab = hbuf + (long)m0g * 768;
    Wb = ew1t + (long)wsel * (1536L * 768) + (long)n0 * 768;
    bp = eb1 + (long)wsel * 1536 + n0;
    outp = hid + (long)pair * (512L * 1536) + (long)(by * 128) * 1536 + n0;
    ldo = 1536;
    wscale = wslot[pair];
  }

  f32x4 zero = {0.f, 0.f, 0.f, 0.f};
  f32x4 acc[4][4];
  #pragma unroll
  for (int i = 0; i < 4; i++)
    #pragma unroll
    for (int j = 0; j < 4; j++) acc[i][j] = zero;

  GEMM_CORE4(Ab, Wb, 768, 768, 768);

  // LDS-staged vectorized epilogue: acc -> f16 scratch[128][128] -> 16B stores.
  __syncthreads();
  #pragma unroll
  for (int i = 0; i < 4; i++)
    #pragma unroll
    for (int j = 0; j < 4; j++)
      #pragma unroll
      for (int r = 0; r < 4; r++) {
        const int rr = wm + i * 16 + q4 * 4 + r;
        const int cc = wn + j * 16 + lr;
        float v = acc[i][j][r] + bp[cc];
        smem[rr * 128 + cc] = (f16)(gelu_fast(v) * wscale);
      }
  __syncthreads();
  {
    const int rsub = tid >> 4;          // 0..15
    const int cseg = (tid & 15) * 8;    // f16 col, 16B segments
    #pragma unroll
    for (int g = 0; g < 8; g++) {
      const int row = g * 16 + rsub;
      *(f16x8*)&outp[(long)row * ldo + cseg] =
          *(const f16x8*)&smem[row * 128 + cseg];
    }
  }
}

// ---------------------------------------------------------------------------
// Merged FFN2: shared FFN2 (192 blocks, K=3072) + expert FFN2 (768 blocks,
// K=1536) in one 960-block launch. Distance-2 core; vectorized epilogues.
//   shared: dout[row][col] = x2 + shid@shw2t + shb2         (fp32, 2 passes)
//   expert: eo[pair][row][col] = hid@ew2t[e] + w_k*eb2[e]   (f16)
// ---------------------------------------------------------------------------
__global__ __launch_bounds__(256) void gemm_ffn2(
    const f16* __restrict__ shid, const f16* __restrict__ shw2t,
    const float* __restrict__ shb2, const float* __restrict__ x2,
    const f16* __restrict__ hid, const f16* __restrict__ ew2t,
    const float* __restrict__ eb2,
    const int* __restrict__ topk, const float* __restrict__ wslot,
    float* __restrict__ dout, f16* __restrict__ eo)
{
  __shared__ f16 smem[3 * 4096 * 2];    // 48KB: 3-buf staging; epilogue scratch
  f16* sA = smem;
  f16* sB = smem + 3 * 4096;
  const int orig = blockIdx.x;          // 960 = 8 XCDs x 120
  const int xcd = orig & 7, slot = orig >> 3;

  const int tid = threadIdx.x;
  const int f = tid * 8;
  const int fr = f >> 5, fc = f & 31;
  const int lane = tid & 63, wid = tid >> 6;
  const int wm = (wid >> 1) * 64, wn = (wid & 1) * 64;
  const int lr = lane & 15, q4 = lane >> 4;

  const bool shared_role = (slot < 24);
  const f16* Ab;
  const f16* Wb;
  int m0, n0, pair = 0, wsel = 0;

  if (shared_role) {                    // l in [0,192)
    const int l = xcd * 24 + slot;
    const int bx = l % 6, by = l / 6;   // n-tile 0..5, m-tile 0..31
    n0 = bx * 128; m0 = by * 128;
    Ab = shid + (long)m0 * 3072;
    Wb = shw2t + (long)n0 * 3072;
  } else {                              // l in [0,768)
    const int l = xcd * 96 + (slot - 24);
    const int bx = l % 6;
    const int u = l / 6;
    const int by = u & 3; pair = u >> 2;
    wsel = topk[pair];
    n0 = bx * 128; m0 = by * 128;       // m0 local within 512-row slot
    Ab = hid + (long)pair * (512L * 1536) + (long)m0 * 1536;
    Wb = ew2t + (long)wsel * (768L * 1536) + (long)n0 * 1536;
  }

  f32x4 zero = {0.f, 0.f, 0.f, 0.f};
  f32x4 acc[4][4];
  #pragma unroll
  for (int i = 0; i < 4; i++)
    #pragma unroll
    for (int j = 0; j < 4; j++) acc[i][j] = zero;

  if (shared_role) {
    GEMM_CORE3(Ab, Wb, 3072, 3072, 3072);
  } else {
    GEMM_CORE3(Ab, Wb, 1536, 1536, 1536);
  }

  __syncthreads();
  if (shared_role) {
    // fp32 output in two 64-row passes through scratch.
    float* sf = (float*)smem;           // 64 x 128 f32
    float* op = dout + (long)m0 * 768 + n0;
    const float* rp = x2 + (long)m0 * 768 + n0;
    const float* bp = shb2 + n0;
    #pragma unroll
    for (int p = 0; p < 2; p++) {
      if ((wid >> 1) == p) {
        #pragma unroll
        for (int i = 0; i < 4; i++)
          #pragma unroll
          for (int j = 0; j < 4; j++)
            #pragma unroll
            for (int r = 0; r < 4; r++)
              sf[(i * 16 + q4 * 4 + r) * 128 + wn + j * 16 + lr] = acc[i][j][r];
      }
      __syncthreads();
      #pragma unroll
      for (int g = 0; g < 8; g++) {
        const int rl = g * 8 + (tid >> 5);
        const int c4 = (tid & 31) * 4;
        const int grow = p * 64 + rl;
        f32x4 v = *(const f32x4*)&sf[rl * 128 + c4];
        const f32x4 rv = *(const f32x4*)&rp[(long)grow * 768 + c4];
        const f32x4 bv = *(const f32x4*)&bp[c4];
        v = v + rv + bv;
        *(f32x4*)&op[(long)grow * 768 + c4] = v;
      }
      __syncthreads();
    }
  } else {
    const float wscale = wslot[pair];
    const float* bp = eb2 + (long)wsel * 768 + n0;
    f16* op = eo + (long)pair * (512L * 768) + (long)m0 * 768 + n0;
    #pragma unroll
    for (int i = 0; i < 4; i++)
      #pragma unroll
      for (int j = 0; j < 4; j++)
        #pragma unroll
        for (int r = 0; r < 4; r++) {
          const int rr = wm + i * 16 + q4 * 4 + r;
          const int cc = wn + j * 16 + lr;
          smem[rr * 128 + cc] = (f16)(acc[i][j][r] + wscale * bp[cc]);
        }
    __syncthreads();
    const int rsub = tid >> 4;
    const int cseg = (tid & 15) * 8;
    #pragma unroll
    for (int g = 0; g < 8; g++) {
      const int row = g * 16 + rsub;
      *(f16x8*)&op[(long)row * 768 + cseg] =
          *(const f16x8*)&smem[row * 128 + cseg];
    }
  }
}

// ---------------------------------------------------------------------------
// Fused attention per (b*h, q-tile of 64). P lives in LDS (XOR-swizzled);
// each wave touches only its own 16 q-rows -> no barrier needed.
// ---------------------------------------------------------------------------
__device__ __forceinline__ int pswz(int row, int col) {
  return row * 512 + (col ^ ((row & 7) << 3));
}

__global__ __launch_bounds__(256) void attn_kernel(
    const f16* __restrict__ Q, const f16* __restrict__ Kt,
    const f16* __restrict__ Vt, f16* __restrict__ AO)
{
  __shared__ f16 Ps[64 * 512];
  const int bh = blockIdx.x;
  const int qt = blockIdx.y;
  const int t = threadIdx.x;
  const int lane = t & 63, w = t >> 6;
  const int lr = lane & 15, q4 = lane >> 4;
  const int r0 = qt * 64 + w * 16;
  const int lrow0 = w * 16;
  const f16* Qh = Q + (long)bh * 512 * 64;
  const f16* Kh = Kt + (long)bh * 512 * 64;

  f32x4 zero = {0.f, 0.f, 0.f, 0.f};
  f32x4 acc[32];
  #pragma unroll
  for (int i = 0; i < 32; i++) acc[i] = zero;

  #pragma unroll
  for (int kk = 0; kk < 2; kk++) {
    f16x8 a = *(const f16x8*)&Qh[(r0 + lr) * 64 + kk * 32 + q4 * 8];
    #pragma unroll
    for (int nt = 0; nt < 32; nt++) {
      f16x8 b = *(const f16x8*)&Kh[(nt * 16 + lr) * 64 + kk * 32 + q4 * 8];
      acc[nt] = mfma16(a, b, acc[nt]);
    }
  }

  const float cscale = 0.125f * 1.44269504089f;
  #pragma unroll
  for (int r = 0; r < 4; r++) {
    float m = -1e30f;
    #pragma unroll
    for (int nt = 0; nt < 32; nt++) m = fmaxf(m, acc[nt][r]);
    #pragma unroll
    for (int o = 1; o < 16; o <<= 1) m = fmaxf(m, __shfl_xor(m, o, 64));
    float s = 0.f;
    #pragma unroll
    for (int nt = 0; nt < 32; nt++) {
      float e = exp2f((acc[nt][r] - m) * cscale);
      acc[nt][r] = e; s += e;
    }
    #pragma unroll
    for (int o = 1; o < 16; o <<= 1) s += __shfl_xor(s, o, 64);
    const float inv = 1.f / s;
    const int lrow = lrow0 + q4 * 4 + r;
    #pragma unroll
    for (int nt = 0; nt < 32; nt++)
      Ps[pswz(lrow, nt * 16 + lr)] = (f16)(acc[nt][r] * inv);
  }

  const f16* Vh = Vt + (long)bh * 64 * 512;
  f32x4 o4[4];
  #pragma unroll
  for (int i = 0; i < 4; i++) o4[i] = zero;
  #pragma unroll
  for (int kk = 0; kk < 16; kk++) {
    f16x8 a = *(const f16x8*)&Ps[pswz(lrow0 + lr, kk * 32 + q4 * 8)];
    #pragma unroll
    for (int nt = 0; nt < 4; nt++) {
      f16x8 b = *(const f16x8*)&Vh[(nt * 16 + lr) * 512 + kk * 32 + q4 * 8];
      o4[nt] = mfma16(a, b, o4[nt]);
    }
  }
  const int b_ = bh / 12, h_ = bh - b_ * 12;
  #pragma unroll
  for (int nt = 0; nt < 4; nt++)
    #pragma unroll
    for (int r = 0; r < 4; r++) {
      const int rowg = r0 + q4 * 4 + r;
      AO[((long)(b_ * 512 + rowg)) * 768 + h_ * 64 + nt * 16 + lr] = (f16)o4[nt][r];
    }
}

// ---------------------------------------------------------------------------
// Router stage 1: partial sums of (x-m)*r over 32-row chunks. part[b][c][768].
// ---------------------------------------------------------------------------
__global__ __launch_bounds__(256) void router_reduce(
    const float* __restrict__ x2, const float* __restrict__ lnm,
    const float* __restrict__ lnr, float* __restrict__ part)
{
  const int c = blockIdx.x, b = blockIdx.y, t = threadIdx.x;
  float a0 = 0.f, a1 = 0.f, a2 = 0.f;
  #pragma unroll 4
  for (int s = 0; s < 32; s++) {
    const long base = (long)b * 512 + c * 32 + s;
    const float m = lnm[base], r = lnr[base];
    const float* xr = x2 + base * 768;
    a0 += (xr[t] - m) * r;
    a1 += (xr[t + 256] - m) * r;
    a2 += (xr[t + 512] - m) * r;
  }
  float* pr = part + ((long)b * 16 + c) * 768;
  pr[t] = a0; pr[t + 256] = a1; pr[t + 512] = a2;
}

// ---------------------------------------------------------------------------
// Router stage 2: fold partials -> seq_repr (fp32, global).
// ---------------------------------------------------------------------------
__global__ __launch_bounds__(256) void router_seq(
    const float* __restrict__ part, const float* __restrict__ g2,
    const float* __restrict__ b2ln, float* __restrict__ seqg)
{
  const int b = blockIdx.x, t = threadIdx.x;
  const float* pb = part + (long)b * 16 * 768;
  #pragma unroll
  for (int i = 0; i < 3; i++) {
    const int j = t + 256 * i;
    float a = 0.f;
    #pragma unroll
    for (int c = 0; c < 16; c++) a += pb[c * 768 + j];
    seqg[b * 768 + j] = a * (1.f / 512.f) * g2[j] + b2ln[j];
  }
}

// ---------------------------------------------------------------------------
// Router stage 3: MLP1 partials over 48-deep d-slices.
// ---------------------------------------------------------------------------
__global__ __launch_bounds__(256) void router_mlp1(
    const float* __restrict__ seqg, const float* __restrict__ rw1,
    float* __restrict__ pmlp)
{
  const int c = blockIdx.x, b = blockIdx.y, t = threadIdx.x;
  const float* sq = seqg + b * 768 + c * 48;
  float a0 = 0.f, a1 = 0.f, a2 = 0.f;
  #pragma unroll 8
  for (int d = 0; d < 48; d++) {
    const float s = sq[d];
    const float* wr = rw1 + (long)(c * 48 + d) * 768;
    a0 += s * wr[t];
    a1 += s * wr[t + 256];
    a2 += s * wr[t + 512];
  }
  float* pr = pmlp + ((long)b * 16 + c) * 768;
  pr[t] = a0; pr[t + 256] = a1; pr[t + 512] = a2;
}

// ---------------------------------------------------------------------------
// Router stage 4: fold MLP1 partials + bias + gelu (exact fp32) -> g1g.
// ---------------------------------------------------------------------------
__global__ __launch_bounds__(256) void router_fold(
    const float* __restrict__ pmlp, const float* __restrict__ rb1,
    float* __restrict__ g1g)
{
  const int b = blockIdx.x, t = threadIdx.x;
  const float* pb = pmlp + (long)b * 16 * 768;
  #pragma unroll
  for (int i = 0; i < 3; i++) {
    const int j = t + 256 * i;
    float a = rb1[j];
    #pragma unroll
    for (int c = 0; c < 16; c++) a += pb[c * 768 + j];
    g1g[b * 768 + j] = 0.5f * a * (1.0f + erff(a * 0.70710678118654752f));
  }
}

// ---------------------------------------------------------------------------
// Router stage 5: logits; softmax; top4; renorm (fp32 exact selection).
// ---------------------------------------------------------------------------
__global__ __launch_bounds__(256) void router_top(
    const float* __restrict__ g1g, const float* __restrict__ rw2,
    const float* __restrict__ rb2, float* __restrict__ wslot,
    int* __restrict__ topkIdx)
{
  __shared__ float lg[14];
  const int b = blockIdx.x, t = threadIdx.x;
  const int e = t >> 4, sub = t & 15;
  if (e < 14) {
    float a = 0.f;
    #pragma unroll
    for (int i = 0; i < 48; i++) {
      const int d = sub + 16 * i;
      a += g1g[b * 768 + d] * rw2[d * 14 + e];
    }
    #pragma unroll
    for (int o = 1; o < 16; o <<= 1) a += __shfl_xor(a, o, 64);
    if (sub == 0) lg[e] = a + rb2[e];
  }
  __syncthreads();
  if (t == 0) {
    float mx = -1e30f;
    for (int ee = 0; ee < 14; ee++) mx = fmaxf(mx, lg[ee]);
    float p[14], s = 0.f;
    for (int ee = 0; ee < 14; ee++) { p[ee] = expf(lg[ee] - mx); s += p[ee]; }
    for (int ee = 0; ee < 14; ee++) p[ee] /= s;
    int idx[4]; float val[4]; bool used[14];
    for (int ee = 0; ee < 14; ee++) used[ee] = false;
    for (int k = 0; k < 4; k++) {
      int best = -1; float bv = -1.f;
      for (int ee = 0; ee < 14; ee++)
        if (!used[ee] && p[ee] > bv) { bv = p[ee]; best = ee; }
      used[best] = true; idx[k] = best; val[k] = bv;
    }
    const float m2 = val[0];
    float ss = 0.f, e4[4];
    for (int k = 0; k < 4; k++) { e4[k] = expf(val[k] - m2); ss += e4[k]; }
    for (int k = 0; k < 4; k++) {
      wslot[b * 4 + k] = e4[k] / ss;
      topkIdx[b * 4 + k] = idx[k];
    }
  }
}

// ---------------------------------------------------------------------------
// Final combine (vectorized): out += eo0+eo1+eo2+eo3, 4 elems/thread.
// ---------------------------------------------------------------------------
__global__ __launch_bounds__(256) void combine_kernel(
    const f16* __restrict__ eo, float* __restrict__ out)
{
  const long i4 = ((long)blockIdx.x * 256 + threadIdx.x) * 4;
  const long b = i4 / (512L * 768);
  const long loc = i4 - b * (512L * 768);
  const f16* e0 = eo + b * 4 * (512L * 768) + loc;
  f32x4 v = *(const f32x4*)&out[i4];
  #pragma unroll
  for (int s = 0; s < 4; s++) {
    const f16x4 ev = *(const f16x4*)&e0[s * (512L * 768)];
    v.x += (float)ev[0];
    v.y += (float)ev[1];
    v.z += (float)ev[2];
    v.w += (float)ev[3];
  }
  *(f32x4*)&out[i4] = v;
}

// ---------------------------------------------------------------------------
// Workspace layout (bytes). Weights persistent; activations alias.
// Total ~191.5 MB.
// ---------------------------------------------------------------------------
static const long OFF_X2    = 0L;                       // 12582912
static const long OFF_LNM   = 12582912L;
static const long OFF_LNR   = OFF_LNM + 16384L;
static const long OFF_WSLOT = OFF_LNR + 16384L;
static const long OFF_TOPK  = OFF_WSLOT + 256L;
static const long OFF_PART  = OFF_TOPK + 256L;          // 393216
static const long OFF_SEQG  = OFF_PART + 393216L;
static const long OFF_PMLP  = OFF_SEQG + 24576L;
static const long OFF_G1G   = OFF_PMLP + 393216L;       // ends 13451776
// persistent transposed weights
static const long W_QKVWT  = 13631488L;                 // 3538944
static const long W_PROJWT = W_QKVWT + 3538944L;        // 1179648
static const long W_EW1T   = W_PROJWT + 1179648L;       // 33030144
static const long W_EW2T   = W_EW1T + 33030144L;        // 33030144
static const long W_SHW1T  = W_EW2T + 33030144L;        // 4718592
static const long W_SHW2T  = W_SHW1T + 4718592L;        // 4718592 -> 93847552
// activation region (phase A aliases phase B)
static const long OFF_ACT  = 93847552L;
static const long A_H1     = OFF_ACT;                   // 6291456
static const long A_Q      = OFF_ACT + 6291456L;        // 3 x 6291456
static const long A_AO     = A_Q + 18874368L;           // 6291456
static const long B_H      = OFF_ACT;                   // 6291456
static const long B_HID    = OFF_ACT + 6291456L;        // 50331648
static const long B_SHID   = B_HID + 50331648L;         // 25165824
static const long B_EO     = B_SHID + 25165824L;        // 25165824 -> ends 200802304

extern "C" void kernel_launch(void* const* d_in, const int* in_sizes, int n_in,
                              void* d_out, int out_size, void* d_ws, size_t ws_size,
                              hipStream_t stream) {
  const float* x     = (const float*)d_in[0];
  const float* ln1g  = (const float*)d_in[1];
  const float* ln1b  = (const float*)d_in[2];
  const float* qkvw  = (const float*)d_in[3];
  const float* projw = (const float*)d_in[4];
  const float* projb = (const float*)d_in[5];
  const float* ln2g  = (const float*)d_in[6];
  const float* ln2b  = (const float*)d_in[7];
  const float* rw1   = (const float*)d_in[8];
  const float* rb1   = (const float*)d_in[9];
  const float* rw2   = (const float*)d_in[10];
  const float* rb2   = (const float*)d_in[11];
  const float* ew1   = (const float*)d_in[12];
  const float* eb1   = (const float*)d_in[13];
  const float* ew2   = (const float*)d_in[14];
  const float* eb2   = (const float*)d_in[15];
  const float* shw1  = (const float*)d_in[16];
  const float* shb1  = (const float*)d_in[17];
  const float* shw2  = (const float*)d_in[18];
  const float* shb2  = (const float*)d_in[19];

  char* ws = (char*)d_ws;
  float* x2    = (float*)(ws + OFF_X2);
  float* lnm   = (float*)(ws + OFF_LNM);
  float* lnr   = (float*)(ws + OFF_LNR);
  float* wslot = (float*)(ws + OFF_WSLOT);
  int*   topk  = (int*)(ws + OFF_TOPK);
  float* part  = (float*)(ws + OFF_PART);
  float* seqg  = (float*)(ws + OFF_SEQG);
  float* pmlp  = (float*)(ws + OFF_PMLP);
  float* g1g   = (float*)(ws + OFF_G1G);
  f16* qkvwt  = (f16*)(ws + W_QKVWT);
  f16* projwt = (f16*)(ws + W_PROJWT);
  f16* ew1t   = (f16*)(ws + W_EW1T);
  f16* ew2t   = (f16*)(ws + W_EW2T);
  f16* shw1t  = (f16*)(ws + W_SHW1T);
  f16* shw2t  = (f16*)(ws + W_SHW2T);
  f16* h1     = (f16*)(ws + A_H1);
  f16* Qb     = (f16*)(ws + A_Q);
  f16* aob    = (f16*)(ws + A_AO);
  f16* hbuf   = (f16*)(ws + B_H);
  f16* hid    = (f16*)(ws + B_HID);
  f16* shid   = (f16*)(ws + B_SHID);
  f16* eo     = (f16*)(ws + B_EO);

  // ---- all weight transposes in one launch ----
  TransArgs ta;
  ta.src[0] = qkvw;  ta.dst[0] = qkvwt;  ta.rows[0] = 768;  ta.cols[0] = 2304;
  ta.src[1] = projw; ta.dst[1] = projwt; ta.rows[1] = 768;  ta.cols[1] = 768;
  ta.src[2] = ew1;   ta.dst[2] = ew1t;   ta.rows[2] = 768;  ta.cols[2] = 1536;
  ta.src[3] = ew2;   ta.dst[3] = ew2t;   ta.rows[3] = 1536; ta.cols[3] = 768;
  ta.src[4] = shw1;  ta.dst[4] = shw1t;  ta.rows[4] = 768;  ta.cols[4] = 3072;
  ta.src[5] = shw2;  ta.dst[5] = shw2t;  ta.rows[5] = 3072; ta.cols[5] = 768;
  ta.start[0] = 0;     ta.start[1] = 1728;  ta.start[2] = 2304;
  ta.start[3] = 18432; ta.start[4] = 34560; ta.start[5] = 36864;
  ta.start[6] = 39168;
  transpose_all<<<39168, 256, 0, stream>>>(ta);

  // ---- Phase A: attention ----
  ln_kernel<<<4096, 256, 0, stream>>>(x, ln1g, ln1b, h1, lnm, lnr);
  gemm_bt<EPI_QKV><<<dim3(18, 32, 1), 256, 0, stream>>>(
      h1, 768, 0, 0, qkvwt, 0, nullptr, 0, nullptr, (void*)Qb, 0, 0, nullptr);
  attn_kernel<<<dim3(96, 8, 1), 256, 0, stream>>>(Qb, Qb + 3145728, Qb + 6291456, aob);
  gemm_bt<EPI_RESID><<<dim3(6, 32, 1), 256, 0, stream>>>(
      aob, 768, 0, 0, projwt, 0, projb, 0, nullptr, (void*)x2, 0, 768, x);

  // ---- Phase B: MoE ----
  ln_kernel<<<4096, 256, 0, stream>>>(x2, ln2g, ln2b, hbuf, lnm, lnr);
  router_reduce<<<dim3(16, 8, 1), 256, 0, stream>>>(x2, lnm, lnr, part);
  router_seq<<<8, 256, 0, stream>>>(part, ln2g, ln2b, seqg);
  router_mlp1<<<dim3(16, 8, 1), 256, 0, stream>>>(seqg, rw1, pmlp);
  router_fold<<<8, 256, 0, stream>>>(pmlp, rb1, g1g);
  router_top<<<8, 256, 0, stream>>>(g1g, rw2, rb2, wslot, topk);
  // merged FFN1: shared (768 blocks) + expert (1536 blocks), K=768 uniform
  gemm_ffn1<<<2304, 256, 0, stream>>>(hbuf, shw1t, shb1, ew1t, eb1,
                                      topk, wslot, shid, hid);
  // merged FFN2: shared (192 blocks, K=3072) + expert (768 blocks, K=1536)
  gemm_ffn2<<<960, 256, 0, stream>>>(shid, shw2t, shb2, x2, hid, ew2t, eb2,
                                     topk, wslot, (float*)d_out, eo);
  combine_kernel<<<3072, 256, 0, stream>>>(eo, (float*)d_out);
}

// Round 7
// 565.001 us; speedup vs baseline: 1.0534x; 1.0057x over previous
//
#include <hip/hip_runtime.h>
#include <hip/hip_bf16.h>

// ---------------------------------------------------------------------------
// MoE transformer block, MI355X gfx950.
// B=8 S=512 D=768 H=12 dh=64 E=14 K=4 HID=1536 SH=3072
// R12: (1) ffn1 reverted to distance-2 (R11's distance-3 regressed 98->110:
//      64KB LDS halved residency -> occupancy 27.6->19.5 AND FETCH 80->110MB
//      from lost L2 sharing; d2@48KB is the sweet spot for this tile).
//      (2) LDS bank-conflict swizzle in the shared GEMM macros, both-sides:
//      stage pre-swizzles the GLOBAL source column (seg ^= (row>>1)&3, LDS
//      dest stays linear as global_load_lds requires); ds_read applies the
//      same XOR (seg' = q4 ^ ((lr>>1)&3)). Old pattern: 64B row stride ->
//      4-way conflict in every 8-lane group (8.26M conflict-cycles on ffn1
//      alone). New: any 8 consecutive lanes cover all 32 banks.
//      Keeps: merged FFN1/FFN2 grids, XCD grouping, counted-vmcnt d2 cores
//      with 0x38F-relaxed tails, vectorized LDS-staged epilogues, w_k in
//      FFN1 epilogue, fast GELU, LDS attn, fused transpose.
// ---------------------------------------------------------------------------

typedef _Float16 f16x8 __attribute__((ext_vector_type(8)));
typedef _Float16 f16x4 __attribute__((ext_vector_type(4)));
typedef float f32x4 __attribute__((ext_vector_type(4)));
typedef _Float16 f16;

// tanh-form GELU: one v_exp_f32; |diff vs erf-gelu| <= ~3e-3.
__device__ __forceinline__ float gelu_fast(float x) {
  const float k2l2e = 2.f * 0.7978845608028654f * 1.4426950408889634f;
  float u = (x + 0.044715f * x * x * x) * k2l2e;
  float t = exp2f(u);
  return x * (1.f - 1.f / (t + 1.f));
}

__device__ __forceinline__ f32x4 mfma16(f16x8 a, f16x8 b, f32x4 c) {
  return __builtin_amdgcn_mfma_f32_16x16x32_f16(a, b, c, 0, 0, 0);
}

// async global->LDS, 16B per lane; LDS dst must be wave-uniform base + lane*16
#define ASYNC_CP16(g, l)                                            \
  __builtin_amdgcn_global_load_lds(                                 \
      (const __attribute__((address_space(1))) void*)(g),           \
      (__attribute__((address_space(3))) void*)(l), 16, 0, 0)

// Stage one 128x32 A-tile and B-tile k-slice into LDS buffer `buf` (4 loads).
// Source column uses the swizzled segment fcw: LDS[row][seg] holds
// global[row][seg ^ ((row>>1)&3)]. Rows fr and fr+64 share the same swizzle
// value ((fr+64)>>1 == fr>>1 + 32 == fr>>1 mod 4). LDS dest stays linear.
#define GEMM_STAGE(AB, WB, LDA, LDB, koff, buf)                               \
  ASYNC_CP16(&(AB)[(long)fr * (LDA) + (koff) + fcw],        &sA[(buf) * 4096 + f]);        \
  ASYNC_CP16(&(AB)[(long)(fr + 64) * (LDA) + (koff) + fcw], &sA[(buf) * 4096 + f + 2048]); \
  ASYNC_CP16(&(WB)[(long)fr * (LDB) + (koff) + fcw],        &sB[(buf) * 4096 + f]);        \
  ASYNC_CP16(&(WB)[(long)(fr + 64) * (LDB) + (koff) + fcw], &sB[(buf) * 4096 + f + 2048]);

// ds_read current buffer + 16 MFMAs. Reads use the matching XOR'd segment
// sv = (q4 ^ ((lr>>1)&3))*8  (row = wm/wn + i*16 + lr; (row>>1)&3 ==
// (lr>>1)&3 since wm/wn,i*16 are multiples of 16). Conflict-free: any 8
// consecutive lanes land on 8 distinct bank quads.
#define GEMM_COMPUTE(bufidx)                                                  \
  {                                                                           \
    f16x8 av[4], bv[4];                                                       \
    _Pragma("unroll")                                                         \
    for (int i = 0; i < 4; i++)                                               \
      av[i] = *(const f16x8*)&sA[(bufidx) * 4096 + (wm + i * 16 + lr) * 32 + sv]; \
    _Pragma("unroll")                                                         \
    for (int j = 0; j < 4; j++)                                               \
      bv[j] = *(const f16x8*)&sB[(bufidx) * 4096 + (wn + j * 16 + lr) * 32 + sv]; \
    _Pragma("unroll")                                                         \
    for (int i = 0; i < 4; i++)                                               \
      _Pragma("unroll")                                                       \
      for (int j = 0; j < 4; j++) acc[i][j] = mfma16(av[i], bv[j], acc[i][j]); \
  }

// Distance-2 pipelined core (3 buffers, counted vmcnt). R10-validated
// (ffn1 108->98us, VALUBusy 49%). Per step k: vmcnt(4) -> s_barrier ->
// sched_barrier(0) [pins ds_reads below barrier] -> stage k+2 into (k-1)%3
// -> ds_read k%3 -> MFMA -> sched_barrier(0x38F) [only VMEM blocked from
// crossing: keeps vmcnt counting exact, VALU/MFMA/DS free to schedule].
// Overwrite safety: all waves' step-(k-1) ds_reads retire before barrier k.
#define GEMM_CORE3(AB, WB, LDA, LDB, KK)                                      \
  {                                                                           \
    GEMM_STAGE(AB, WB, LDA, LDB, 0, 0)                                        \
    GEMM_STAGE(AB, WB, LDA, LDB, 32, 1)                                       \
    int cur = 0;                                                              \
    for (int k0 = 0; k0 < (KK); k0 += 32) {                                   \
      if (k0 + 32 < (KK)) {                                                   \
        asm volatile("s_waitcnt vmcnt(4)" ::: "memory");                      \
      } else {                                                                \
        asm volatile("s_waitcnt vmcnt(0)" ::: "memory");                      \
      }                                                                       \
      __builtin_amdgcn_s_barrier();                                           \
      __builtin_amdgcn_sched_barrier(0);                                      \
      if (k0 + 64 < (KK)) {                                                   \
        const int nb = (cur + 2 >= 3) ? cur - 1 : cur + 2;                    \
        GEMM_STAGE(AB, WB, LDA, LDB, k0 + 64, nb)                             \
      }                                                                       \
      GEMM_COMPUTE(cur)                                                       \
      __builtin_amdgcn_sched_barrier(0x38F);                                  \
      cur = (cur == 2) ? 0 : cur + 1;                                         \
    }                                                                         \
  }

// ---------------------------------------------------------------------------
// LayerNorm: fp32 in -> f16 out, saves per-row mean and rstd (for router).
// ---------------------------------------------------------------------------
__global__ __launch_bounds__(256) void ln_kernel(
    const float* __restrict__ x, const float* __restrict__ g,
    const float* __restrict__ bt, f16* __restrict__ out,
    float* __restrict__ mout, float* __restrict__ rout)
{
  const int row = blockIdx.x;
  const float* xr = x + (long)row * 768;
  const int t = threadIdx.x;
  float v0 = xr[t], v1 = xr[t + 256], v2 = xr[t + 512];
  __shared__ float sb[8];
  float s = v0 + v1 + v2;
  #pragma unroll
  for (int o = 32; o > 0; o >>= 1) s += __shfl_xor(s, o, 64);
  const int w = t >> 6;
  if ((t & 63) == 0) sb[w] = s;
  __syncthreads();
  const float mean = (sb[0] + sb[1] + sb[2] + sb[3]) * (1.0f / 768.0f);
  const float d0 = v0 - mean, d1 = v1 - mean, d2 = v2 - mean;
  float q = d0 * d0 + d1 * d1 + d2 * d2;
  #pragma unroll
  for (int o = 32; o > 0; o >>= 1) q += __shfl_xor(q, o, 64);
  if ((t & 63) == 0) sb[4 + w] = q;
  __syncthreads();
  const float var = (sb[4] + sb[5] + sb[6] + sb[7]) * (1.0f / 768.0f);
  const float rstd = rsqrtf(var + 1e-5f);
  f16* orow = out + (long)row * 768;
  orow[t]       = (f16)(d0 * rstd * g[t]       + bt[t]);
  orow[t + 256] = (f16)(d1 * rstd * g[t + 256] + bt[t + 256]);
  orow[t + 512] = (f16)(d2 * rstd * g[t + 512] + bt[t + 512]);
  if (t == 0) { mout[row] = mean; rout[row] = rstd; }
}

// ---------------------------------------------------------------------------
// Fused transpose of all 6 weight matrices, fp32 [r][c] -> f16 [c][r].
// ---------------------------------------------------------------------------
struct TransArgs {
  const float* src[6];
  f16* dst[6];
  int rows[6], cols[6];
  int start[7];
};

__global__ __launch_bounds__(256) void transpose_all(TransArgs ta) {
  const int bid = blockIdx.x;
  int m = 0;
  #pragma unroll
  for (int i = 1; i < 6; i++) if (bid >= ta.start[i]) m = i;
  const int rows = ta.rows[m], cols = ta.cols[m];
  const int tilesC = cols >> 5;
  const int perB = (rows >> 5) * tilesC;
  int local = bid - ta.start[m];
  const int z = local / perB; local -= z * perB;
  const int tr = local / tilesC, tc = local - tr * tilesC;
  const float* inb = ta.src[m] + (long)z * rows * cols;
  f16* outb = ta.dst[m] + (long)z * rows * cols;
  const int c0 = tc * 32, r0 = tr * 32;
  __shared__ float tile[32][33];
  const int tx = threadIdx.x & 31, ty = threadIdx.x >> 5;
  #pragma unroll
  for (int i = 0; i < 32; i += 8)
    tile[ty + i][tx] = inb[(long)(r0 + ty + i) * cols + c0 + tx];
  __syncthreads();
  #pragma unroll
  for (int i = 0; i < 32; i += 8)
    outb[(long)(c0 + ty + i) * rows + r0 + tx] = (f16)tile[tx][ty + i];
}

// ---------------------------------------------------------------------------
// Generic GEMM: C[M,N] = A[M,K] @ W^T   (A f16 row-major, W f16 [N][K]).
// 128x128 tile, BK=32, 4 waves x 64x64. Distance-2 pipelined staging.
// ---------------------------------------------------------------------------
#define EPI_QKV     0
#define EPI_RESID   1

template <int EPI>
__global__ __launch_bounds__(256) void gemm_bt(
    const f16* __restrict__ A, int K, long strideA, int aShift,
    const f16* __restrict__ W, long strideW,
    const float* __restrict__ bias, int strideBias,
    const int* __restrict__ topkIdx,
    void* __restrict__ outv, long strideOut, int ldout,
    const float* __restrict__ resid)
{
  __shared__ f16 sA[3 * 128 * 32];
  __shared__ f16 sB[3 * 128 * 32];
  const int tid = threadIdx.x;
  const int pair = blockIdx.z;
  const int m0 = blockIdx.y * 128;
  const int n0 = blockIdx.x * 128;
  const f16* Ab = A + ((long)(pair >> aShift)) * strideA + (long)m0 * K;
  const int wsel = topkIdx ? topkIdx[pair] : pair;
  const f16* Wb = W + (long)wsel * strideW + (long)n0 * K;

  const int f = tid * 8;
  const int fr = f >> 5;
  const int fcw = (((tid & 3) ^ ((tid >> 3) & 3)) * 8);   // swizzled src seg
  const int lane = tid & 63, wid = tid >> 6;
  const int wm = (wid >> 1) * 64, wn = (wid & 1) * 64;
  const int lr = lane & 15, q4 = lane >> 4;
  const int sv = (q4 ^ ((lr >> 1) & 3)) * 8;              // swizzled read seg

  f32x4 zero = {0.f, 0.f, 0.f, 0.f};
  f32x4 acc[4][4];
  #pragma unroll
  for (int i = 0; i < 4; i++)
    #pragma unroll
    for (int j = 0; j < 4; j++) acc[i][j] = zero;

  GEMM_CORE3(Ab, Wb, K, K, K);

  // Epilogue. C/D layout: col = lane&15, row = (lane>>4)*4 + reg.
  #pragma unroll
  for (int i = 0; i < 4; i++) {
    #pragma unroll
    for (int j = 0; j < 4; j++) {
      #pragma unroll
      for (int r = 0; r < 4; r++) {
        const int row = m0 + wm + i * 16 + q4 * 4 + r;
        const int col = n0 + wn + j * 16 + lr;
        float v = acc[i][j][r];
        if constexpr (EPI == EPI_QKV) {
          f16* qb = (f16*)outv;
          const int i3 = col / 768;
          const int rem = col - i3 * 768;
          const int hh = rem >> 6, dd = rem & 63;
          const int bb = row >> 9, ss = row & 511;
          const long bh = bb * 12 + hh;
          if (i3 == 0)      qb[(bh * 512 + ss) * 64 + dd] = (f16)v;           // Q
          else if (i3 == 1) qb[3145728 + (bh * 512 + ss) * 64 + dd] = (f16)v; // K
          else              qb[6291456 + (bh * 64 + dd) * 512 + ss] = (f16)v; // V^T
        } else {  // EPI_RESID
          float* ob = (float*)outv;
          v += bias[col];
          ob[(long)row * ldout + col] = resid[(long)row * ldout + col] + v;
        }
      }
    }
  }
}

// ---------------------------------------------------------------------------
// Merged FFN1: shared FFN1 (768 blocks) + expert FFN1 (1536 blocks), K=768.
// Distance-2 counted-vmcnt core; LDS-staged vectorized epilogue.
//   shared: shid[row][col] = gelu(hbuf@shw1t + shb1)
//   expert: hid[pair][row][col] = gelu(hbuf_b@ew1t[e] + eb1[e]) * w_k
// ---------------------------------------------------------------------------
__global__ __launch_bounds__(256) void gemm_ffn1(
    const f16* __restrict__ hbuf,
    const f16* __restrict__ shw1t, const float* __restrict__ shb1,
    const f16* __restrict__ ew1t,  const float* __restrict__ eb1,
    const int* __restrict__ topk,  const float* __restrict__ wslot,
    f16* __restrict__ shid, f16* __restrict__ hid)
{
  __shared__ f16 smem[3 * 4096 * 2];    // 48KB: 3-buf staging; epilogue scratch
  f16* sA = smem;
  f16* sB = smem + 3 * 4096;
  const int orig = blockIdx.x;          // 2304 = 8 XCDs x 288
  const int xcd = orig & 7, slot = orig >> 3;

  const int tid = threadIdx.x;
  const int f = tid * 8;
  const int fr = f >> 5;
  const int fcw = (((tid & 3) ^ ((tid >> 3) & 3)) * 8);
  const int lane = tid & 63, wid = tid >> 6;
  const int wm = (wid >> 1) * 64, wn = (wid & 1) * 64;
  const int lr = lane & 15, q4 = lane >> 4;
  const int sv = (q4 ^ ((lr >> 1) & 3)) * 8;

  const f16* Ab;
  const f16* Wb;
  const float* bp;
  f16* outp;
  int ldo;
  float wscale;

  if (slot < 96) {                      // shared role: l in [0,768)
    const int l = xcd * 96 + slot;
    const int bx = l % 24, by = l / 24; // n-tile 0..23, m-tile 0..31
    const int n0 = bx * 128, m0 = by * 128;
    Ab = hbuf + (long)m0 * 768;
    Wb = shw1t + (long)n0 * 768;
    bp = shb1 + n0;
    outp = shid + (long)m0 * 3072 + n0;
    ldo = 3072;
    wscale = 1.f;
  } else {                              // expert role: l in [0,1536)
    const int l = xcd * 192 + (slot - 96);
    const int bx = l % 12;
    const int u = l / 12;
    const int by = u & 3, pair = u >> 2;
    const int wsel = topk[pair];
    const int n0 = bx * 128;
    const int m0g = (pair >> 2) * 512 + by * 128;   // global row in hbuf
    Ab = hbuf + (long)m0g * 768;
    Wb = ew1t + (long)wsel * (1536L * 768) + (long)n0 * 768;
    bp = eb1 + (long)wsel * 1536 + n0;
    outp = hid + (long)pair * (512L * 1536) + (long)(by * 128) * 1536 + n0;
    ldo = 1536;
    wscale = wslot[pair];
  }

  f32x4 zero = {0.f, 0.f, 0.f, 0.f};
  f32x4 acc[4][4];
  #pragma unroll
  for (int i = 0; i < 4; i++)
    #pragma unroll
    for (int j = 0; j < 4; j++) acc[i][j] = zero;

  GEMM_CORE3(Ab, Wb, 768, 768, 768);

  // LDS-staged vectorized epilogue: acc -> f16 scratch[128][128] -> 16B stores.
  __syncthreads();
  #pragma unroll
  for (int i = 0; i < 4; i++)
    #pragma unroll
    for (int j = 0; j < 4; j++)
      #pragma unroll
      for (int r = 0; r < 4; r++) {
        const int rr = wm + i * 16 + q4 * 4 + r;
        const int cc = wn + j * 16 + lr;
        float v = acc[i][j][r] + bp[cc];
        smem[rr * 128 + cc] = (f16)(gelu_fast(v) * wscale);
      }
  __syncthreads();
  {
    const int rsub = tid >> 4;          // 0..15
    const int cseg = (tid & 15) * 8;    // f16 col, 16B segments
    #pragma unroll
    for (int g = 0; g < 8; g++) {
      const int row = g * 16 + rsub;
      *(f16x8*)&outp[(long)row * ldo + cseg] =
          *(const f16x8*)&smem[row * 128 + cseg];
    }
  }
}

// ---------------------------------------------------------------------------
// Merged FFN2: shared FFN2 (192 blocks, K=3072) + expert FFN2 (768 blocks,
// K=1536) in one 960-block launch. Distance-2 core; vectorized epilogues.
//   shared: dout[row][col] = x2 + shid@shw2t + shb2         (fp32, 2 passes)
//   expert: eo[pair][row][col] = hid@ew2t[e] + w_k*eb2[e]   (f16)
// ---------------------------------------------------------------------------
__global__ __launch_bounds__(256) void gemm_ffn2(
    const f16* __restrict__ shid, const f16* __restrict__ shw2t,
    const float* __restrict__ shb2, const float* __restrict__ x2,
    const f16* __restrict__ hid, const f16* __restrict__ ew2t,
    const float* __restrict__ eb2,
    const int* __restrict__ topk, const float* __restrict__ wslot,
    float* __restrict__ dout, f16* __restrict__ eo)
{
  __shared__ f16 smem[3 * 4096 * 2];    // 48KB: 3-buf staging; epilogue scratch
  f16* sA = smem;
  f16* sB = smem + 3 * 4096;
  const int orig = blockIdx.x;          // 960 = 8 XCDs x 120
  const int xcd = orig & 7, slot = orig >> 3;

  const int tid = threadIdx.x;
  const int f = tid * 8;
  const int fr = f >> 5;
  const int fcw = (((tid & 3) ^ ((tid >> 3) & 3)) * 8);
  const int lane = tid & 63, wid = tid >> 6;
  const int wm = (wid >> 1) * 64, wn = (wid & 1) * 64;
  const int lr = lane & 15, q4 = lane >> 4;
  const int sv = (q4 ^ ((lr >> 1) & 3)) * 8;

  const bool shared_role = (slot < 24);
  const f16* Ab;
  const f16* Wb;
  int m0, n0, pair = 0, wsel = 0;

  if (shared_role) {                    // l in [0,192)
    const int l = xcd * 24 + slot;
    const int bx = l % 6, by = l / 6;   // n-tile 0..5, m-tile 0..31
    n0 = bx * 128; m0 = by * 128;
    Ab = shid + (long)m0 * 3072;
    Wb = shw2t + (long)n0 * 3072;
  } else {                              // l in [0,768)
    const int l = xcd * 96 + (slot - 24);
    const int bx = l % 6;
    const int u = l / 6;
    const int by = u & 3; pair = u >> 2;
    wsel = topk[pair];
    n0 = bx * 128; m0 = by * 128;       // m0 local within 512-row slot
    Ab = hid + (long)pair * (512L * 1536) + (long)m0 * 1536;
    Wb = ew2t + (long)wsel * (768L * 1536) + (long)n0 * 1536;
  }

  f32x4 zero = {0.f, 0.f, 0.f, 0.f};
  f32x4 acc[4][4];
  #pragma unroll
  for (int i = 0; i < 4; i++)
    #pragma unroll
    for (int j = 0; j < 4; j++) acc[i][j] = zero;

  if (shared_role) {
    GEMM_CORE3(Ab, Wb, 3072, 3072, 3072);
  } else {
    GEMM_CORE3(Ab, Wb, 1536, 1536, 1536);
  }

  __syncthreads();
  if (shared_role) {
    // fp32 output in two 64-row passes through scratch.
    float* sf = (float*)smem;           // 64 x 128 f32
    float* op = dout + (long)m0 * 768 + n0;
    const float* rp = x2 + (long)m0 * 768 + n0;
    const float* bp = shb2 + n0;
    #pragma unroll
    for (int p = 0; p < 2; p++) {
      if ((wid >> 1) == p) {
        #pragma unroll
        for (int i = 0; i < 4; i++)
          #pragma unroll
          for (int j = 0; j < 4; j++)
            #pragma unroll
            for (int r = 0; r < 4; r++)
              sf[(i * 16 + q4 * 4 + r) * 128 + wn + j * 16 + lr] = acc[i][j][r];
      }
      __syncthreads();
      #pragma unroll
      for (int g = 0; g < 8; g++) {
        const int rl = g * 8 + (tid >> 5);
        const int c4 = (tid & 31) * 4;
        const int grow = p * 64 + rl;
        f32x4 v = *(const f32x4*)&sf[rl * 128 + c4];
        const f32x4 rv = *(const f32x4*)&rp[(long)grow * 768 + c4];
        const f32x4 bv = *(const f32x4*)&bp[c4];
        v = v + rv + bv;
        *(f32x4*)&op[(long)grow * 768 + c4] = v;
      }
      __syncthreads();
    }
  } else {
    const float wscale = wslot[pair];
    const float* bp = eb2 + (long)wsel * 768 + n0;
    f16* op = eo + (long)pair * (512L * 768) + (long)m0 * 768 + n0;
    #pragma unroll
    for (int i = 0; i < 4; i++)
      #pragma unroll
      for (int j = 0; j < 4; j++)
        #pragma unroll
        for (int r = 0; r < 4; r++) {
          const int rr = wm + i * 16 + q4 * 4 + r;
          const int cc = wn + j * 16 + lr;
          smem[rr * 128 + cc] = (f16)(acc[i][j][r] + wscale * bp[cc]);
        }
    __syncthreads();
    const int rsub = tid >> 4;
    const int cseg = (tid & 15) * 8;
    #pragma unroll
    for (int g = 0; g < 8; g++) {
      const int row = g * 16 + rsub;
      *(f16x8*)&op[(long)row * 768 + cseg] =
          *(const f16x8*)&smem[row * 128 + cseg];
    }
  }
}

// ---------------------------------------------------------------------------
// Fused attention per (b*h, q-tile of 64). P lives in LDS (XOR-swizzled);
// each wave touches only its own 16 q-rows -> no barrier needed.
// ---------------------------------------------------------------------------
__device__ __forceinline__ int pswz(int row, int col) {
  return row * 512 + (col ^ ((row & 7) << 3));
}

__global__ __launch_bounds__(256) void attn_kernel(
    const f16* __restrict__ Q, const f16* __restrict__ Kt,
    const f16* __restrict__ Vt, f16* __restrict__ AO)
{
  __shared__ f16 Ps[64 * 512];
  const int bh = blockIdx.x;
  const int qt = blockIdx.y;
  const int t = threadIdx.x;
  const int lane = t & 63, w = t >> 6;
  const int lr = lane & 15, q4 = lane >> 4;
  const int r0 = qt * 64 + w * 16;
  const int lrow0 = w * 16;
  const f16* Qh = Q + (long)bh * 512 * 64;
  const f16* Kh = Kt + (long)bh * 512 * 64;

  f32x4 zero = {0.f, 0.f, 0.f, 0.f};
  f32x4 acc[32];
  #pragma unroll
  for (int i = 0; i < 32; i++) acc[i] = zero;

  #pragma unroll
  for (int kk = 0; kk < 2; kk++) {
    f16x8 a = *(const f16x8*)&Qh[(r0 + lr) * 64 + kk * 32 + q4 * 8];
    #pragma unroll
    for (int nt = 0; nt < 32; nt++) {
      f16x8 b = *(const f16x8*)&Kh[(nt * 16 + lr) * 64 + kk * 32 + q4 * 8];
      acc[nt] = mfma16(a, b, acc[nt]);
    }
  }

  const float cscale = 0.125f * 1.44269504089f;
  #pragma unroll
  for (int r = 0; r < 4; r++) {
    float m = -1e30f;
    #pragma unroll
    for (int nt = 0; nt < 32; nt++) m = fmaxf(m, acc[nt][r]);
    #pragma unroll
    for (int o = 1; o < 16; o <<= 1) m = fmaxf(m, __shfl_xor(m, o, 64));
    float s = 0.f;
    #pragma unroll
    for (int nt = 0; nt < 32; nt++) {
      float e = exp2f((acc[nt][r] - m) * cscale);
      acc[nt][r] = e; s += e;
    }
    #pragma unroll
    for (int o = 1; o < 16; o <<= 1) s += __shfl_xor(s, o, 64);
    const float inv = 1.f / s;
    const int lrow = lrow0 + q4 * 4 + r;
    #pragma unroll
    for (int nt = 0; nt < 32; nt++)
      Ps[pswz(lrow, nt * 16 + lr)] = (f16)(acc[nt][r] * inv);
  }

  const f16* Vh = Vt + (long)bh * 64 * 512;
  f32x4 o4[4];
  #pragma unroll
  for (int i = 0; i < 4; i++) o4[i] = zero;
  #pragma unroll
  for (int kk = 0; kk < 16; kk++) {
    f16x8 a = *(const f16x8*)&Ps[pswz(lrow0 + lr, kk * 32 + q4 * 8)];
    #pragma unroll
    for (int nt = 0; nt < 4; nt++) {
      f16x8 b = *(const f16x8*)&Vh[(nt * 16 + lr) * 512 + kk * 32 + q4 * 8];
      o4[nt] = mfma16(a, b, o4[nt]);
    }
  }
  const int b_ = bh / 12, h_ = bh - b_ * 12;
  #pragma unroll
  for (int nt = 0; nt < 4; nt++)
    #pragma unroll
    for (int r = 0; r < 4; r++) {
      const int rowg = r0 + q4 * 4 + r;
      AO[((long)(b_ * 512 + rowg)) * 768 + h_ * 64 + nt * 16 + lr] = (f16)o4[nt][r];
    }
}

// ---------------------------------------------------------------------------
// Router stage 1: partial sums of (x-m)*r over 32-row chunks. part[b][c][768].
// ---------------------------------------------------------------------------
__global__ __launch_bounds__(256) void router_reduce(
    const float* __restrict__ x2, const float* __restrict__ lnm,
    const float* __restrict__ lnr, float* __restrict__ part)
{
  const int c = blockIdx.x, b = blockIdx.y, t = threadIdx.x;
  float a0 = 0.f, a1 = 0.f, a2 = 0.f;
  #pragma unroll 4
  for (int s = 0; s < 32; s++) {
    const long base = (long)b * 512 + c * 32 + s;
    const float m = lnm[base], r = lnr[base];
    const float* xr = x2 + base * 768;
    a0 += (xr[t] - m) * r;
    a1 += (xr[t + 256] - m) * r;
    a2 += (xr[t + 512] - m) * r;
  }
  float* pr = part + ((long)b * 16 + c) * 768;
  pr[t] = a0; pr[t + 256] = a1; pr[t + 512] = a2;
}

// ---------------------------------------------------------------------------
// Router stage 2: fold partials -> seq_repr (fp32, global).
// ---------------------------------------------------------------------------
__global__ __launch_bounds__(256) void router_seq(
    const float* __restrict__ part, const float* __restrict__ g2,
    const float* __restrict__ b2ln, float* __restrict__ seqg)
{
  const int b = blockIdx.x, t = threadIdx.x;
  const float* pb = part + (long)b * 16 * 768;
  #pragma unroll
  for (int i = 0; i < 3; i++) {
    const int j = t + 256 * i;
    float a = 0.f;
    #pragma unroll
    for (int c = 0; c < 16; c++) a += pb[c * 768 + j];
    seqg[b * 768 + j] = a * (1.f / 512.f) * g2[j] + b2ln[j];
  }
}

// ---------------------------------------------------------------------------
// Router stage 3: MLP1 partials over 48-deep d-slices.
// ---------------------------------------------------------------------------
__global__ __launch_bounds__(256) void router_mlp1(
    const float* __restrict__ seqg, const float* __restrict__ rw1,
    float* __restrict__ pmlp)
{
  const int c = blockIdx.x, b = blockIdx.y, t = threadIdx.x;
  const float* sq = seqg + b * 768 + c * 48;
  float a0 = 0.f, a1 = 0.f, a2 = 0.f;
  #pragma unroll 8
  for (int d = 0; d < 48; d++) {
    const float s = sq[d];
    const float* wr = rw1 + (long)(c * 48 + d) * 768;
    a0 += s * wr[t];
    a1 += s * wr[t + 256];
    a2 += s * wr[t + 512];
  }
  float* pr = pmlp + ((long)b * 16 + c) * 768;
  pr[t] = a0; pr[t + 256] = a1; pr[t + 512] = a2;
}

// ---------------------------------------------------------------------------
// Router stage 4: fold MLP1 partials + bias + gelu (exact fp32) -> g1g.
// ---------------------------------------------------------------------------
__global__ __launch_bounds__(256) void router_fold(
    const float* __restrict__ pmlp, const float* __restrict__ rb1,
    float* __restrict__ g1g)
{
  const int b = blockIdx.x, t = threadIdx.x;
  const float* pb = pmlp + (long)b * 16 * 768;
  #pragma unroll
  for (int i = 0; i < 3; i++) {
    const int j = t + 256 * i;
    float a = rb1[j];
    #pragma unroll
    for (int c = 0; c < 16; c++) a += pb[c * 768 + j];
    g1g[b * 768 + j] = 0.5f * a * (1.0f + erff(a * 0.70710678118654752f));
  }
}

// ---------------------------------------------------------------------------
// Router stage 5: logits; softmax; top4; renorm (fp32 exact selection).
// ---------------------------------------------------------------------------
__global__ __launch_bounds__(256) void router_top(
    const float* __restrict__ g1g, const float* __restrict__ rw2,
    const float* __restrict__ rb2, float* __restrict__ wslot,
    int* __restrict__ topkIdx)
{
  __shared__ float lg[14];
  const int b = blockIdx.x, t = threadIdx.x;
  const int e = t >> 4, sub = t & 15;
  if (e < 14) {
    float a = 0.f;
    #pragma unroll
    for (int i = 0; i < 48; i++) {
      const int d = sub + 16 * i;
      a += g1g[b * 768 + d] * rw2[d * 14 + e];
    }
    #pragma unroll
    for (int o = 1; o < 16; o <<= 1) a += __shfl_xor(a, o, 64);
    if (sub == 0) lg[e] = a + rb2[e];
  }
  __syncthreads();
  if (t == 0) {
    float mx = -1e30f;
    for (int ee = 0; ee < 14; ee++) mx = fmaxf(mx, lg[ee]);
    float p[14], s = 0.f;
    for (int ee = 0; ee < 14; ee++) { p[ee] = expf(lg[ee] - mx); s += p[ee]; }
    for (int ee = 0; ee < 14; ee++) p[ee] /= s;
    int idx[4]; float val[4]; bool used[14];
    for (int ee = 0; ee < 14; ee++) used[ee] = false;
    for (int k = 0; k < 4; k++) {
      int best = -1; float bv = -1.f;
      for (int ee = 0; ee < 14; ee++)
        if (!used[ee] && p[ee] > bv) { bv = p[ee]; best = ee; }
      used[best] = true; idx[k] = best; val[k] = bv;
    }
    const float m2 = val[0];
    float ss = 0.f, e4[4];
    for (int k = 0; k < 4; k++) { e4[k] = expf(val[k] - m2); ss += e4[k]; }
    for (int k = 0; k < 4; k++) {
      wslot[b * 4 + k] = e4[k] / ss;
      topkIdx[b * 4 + k] = idx[k];
    }
  }
}

// ---------------------------------------------------------------------------
// Final combine (vectorized): out += eo0+eo1+eo2+eo3, 4 elems/thread.
// ---------------------------------------------------------------------------
__global__ __launch_bounds__(256) void combine_kernel(
    const f16* __restrict__ eo, float* __restrict__ out)
{
  const long i4 = ((long)blockIdx.x * 256 + threadIdx.x) * 4;
  const long b = i4 / (512L * 768);
  const long loc = i4 - b * (512L * 768);
  const f16* e0 = eo + b * 4 * (512L * 768) + loc;
  f32x4 v = *(const f32x4*)&out[i4];
  #pragma unroll
  for (int s = 0; s < 4; s++) {
    const f16x4 ev = *(const f16x4*)&e0[s * (512L * 768)];
    v.x += (float)ev[0];
    v.y += (float)ev[1];
    v.z += (float)ev[2];
    v.w += (float)ev[3];
  }
  *(f32x4*)&out[i4] = v;
}

// ---------------------------------------------------------------------------
// Workspace layout (bytes). Weights persistent; activations alias.
// Total ~191.5 MB.
// ---------------------------------------------------------------------------
static const long OFF_X2    = 0L;                       // 12582912
static const long OFF_LNM   = 12582912L;
static const long OFF_LNR   = OFF_LNM + 16384L;
static const long OFF_WSLOT = OFF_LNR + 16384L;
static const long OFF_TOPK  = OFF_WSLOT + 256L;
static const long OFF_PART  = OFF_TOPK + 256L;          // 393216
static const long OFF_SEQG  = OFF_PART + 393216L;
static const long OFF_PMLP  = OFF_SEQG + 24576L;
static const long OFF_G1G   = OFF_PMLP + 393216L;       // ends 13451776
// persistent transposed weights
static const long W_QKVWT  = 13631488L;                 // 3538944
static const long W_PROJWT = W_QKVWT + 3538944L;        // 1179648
static const long W_EW1T   = W_PROJWT + 1179648L;       // 33030144
static const long W_EW2T   = W_EW1T + 33030144L;        // 33030144
static const long W_SHW1T  = W_EW2T + 33030144L;        // 4718592
static const long W_SHW2T  = W_SHW1T + 4718592L;        // 4718592 -> 93847552
// activation region (phase A aliases phase B)
static const long OFF_ACT  = 93847552L;
static const long A_H1     = OFF_ACT;                   // 6291456
static const long A_Q      = OFF_ACT + 6291456L;        // 3 x 6291456
static const long A_AO     = A_Q + 18874368L;           // 6291456
static const long B_H      = OFF_ACT;                   // 6291456
static const long B_HID    = OFF_ACT + 6291456L;        // 50331648
static const long B_SHID   = B_HID + 50331648L;         // 25165824
static const long B_EO     = B_SHID + 25165824L;        // 25165824 -> ends 200802304

extern "C" void kernel_launch(void* const* d_in, const int* in_sizes, int n_in,
                              void* d_out, int out_size, void* d_ws, size_t ws_size,
                              hipStream_t stream) {
  const float* x     = (const float*)d_in[0];
  const float* ln1g  = (const float*)d_in[1];
  const float* ln1b  = (const float*)d_in[2];
  const float* qkvw  = (const float*)d_in[3];
  const float* projw = (const float*)d_in[4];
  const float* projb = (const float*)d_in[5];
  const float* ln2g  = (const float*)d_in[6];
  const float* ln2b  = (const float*)d_in[7];
  const float* rw1   = (const float*)d_in[8];
  const float* rb1   = (const float*)d_in[9];
  const float* rw2   = (const float*)d_in[10];
  const float* rb2   = (const float*)d_in[11];
  const float* ew1   = (const float*)d_in[12];
  const float* eb1   = (const float*)d_in[13];
  const float* ew2   = (const float*)d_in[14];
  const float* eb2   = (const float*)d_in[15];
  const float* shw1  = (const float*)d_in[16];
  const float* shb1  = (const float*)d_in[17];
  const float* shw2  = (const float*)d_in[18];
  const float* shb2  = (const float*)d_in[19];

  char* ws = (char*)d_ws;
  float* x2    = (float*)(ws + OFF_X2);
  float* lnm   = (float*)(ws + OFF_LNM);
  float* lnr   = (float*)(ws + OFF_LNR);
  float* wslot = (float*)(ws + OFF_WSLOT);
  int*   topk  = (int*)(ws + OFF_TOPK);
  float* part  = (float*)(ws + OFF_PART);
  float* seqg  = (float*)(ws + OFF_SEQG);
  float* pmlp  = (float*)(ws + OFF_PMLP);
  float* g1g   = (float*)(ws + OFF_G1G);
  f16* qkvwt  = (f16*)(ws + W_QKVWT);
  f16* projwt = (f16*)(ws + W_PROJWT);
  f16* ew1t   = (f16*)(ws + W_EW1T);
  f16* ew2t   = (f16*)(ws + W_EW2T);
  f16* shw1t  = (f16*)(ws + W_SHW1T);
  f16* shw2t  = (f16*)(ws + W_SHW2T);
  f16* h1     = (f16*)(ws + A_H1);
  f16* Qb     = (f16*)(ws + A_Q);
  f16* aob    = (f16*)(ws + A_AO);
  f16* hbuf   = (f16*)(ws + B_H);
  f16* hid    = (f16*)(ws + B_HID);
  f16* shid   = (f16*)(ws + B_SHID);
  f16* eo     = (f16*)(ws + B_EO);

  // ---- all weight transposes in one launch ----
  TransArgs ta;
  ta.src[0] = qkvw;  ta.dst[0] = qkvwt;  ta.rows[0] = 768;  ta.cols[0] = 2304;
  ta.src[1] = projw; ta.dst[1] = projwt; ta.rows[1] = 768;  ta.cols[1] = 768;
  ta.src[2] = ew1;   ta.dst[2] = ew1t;   ta.rows[2] = 768;  ta.cols[2] = 1536;
  ta.src[3] = ew2;   ta.dst[3] = ew2t;   ta.rows[3] = 1536; ta.cols[3] = 768;
  ta.src[4] = shw1;  ta.dst[4] = shw1t;  ta.rows[4] = 768;  ta.cols[4] = 3072;
  ta.src[5] = shw2;  ta.dst[5] = shw2t;  ta.rows[5] = 3072; ta.cols[5] = 768;
  ta.start[0] = 0;     ta.start[1] = 1728;  ta.start[2] = 2304;
  ta.start[3] = 18432; ta.start[4] = 34560; ta.start[5] = 36864;
  ta.start[6] = 39168;
  transpose_all<<<39168, 256, 0, stream>>>(ta);

  // ---- Phase A: attention ----
  ln_kernel<<<4096, 256, 0, stream>>>(x, ln1g, ln1b, h1, lnm, lnr);
  gemm_bt<EPI_QKV><<<dim3(18, 32, 1), 256, 0, stream>>>(
      h1, 768, 0, 0, qkvwt, 0, nullptr, 0, nullptr, (void*)Qb, 0, 0, nullptr);
  attn_kernel<<<dim3(96, 8, 1), 256, 0, stream>>>(Qb, Qb + 3145728, Qb + 6291456, aob);
  gemm_bt<EPI_RESID><<<dim3(6, 32, 1), 256, 0, stream>>>(
      aob, 768, 0, 0, projwt, 0, projb, 0, nullptr, (void*)x2, 0, 768, x);

  // ---- Phase B: MoE ----
  ln_kernel<<<4096, 256, 0, stream>>>(x2, ln2g, ln2b, hbuf, lnm, lnr);
  router_reduce<<<dim3(16, 8, 1), 256, 0, stream>>>(x2, lnm, lnr, part);
  router_seq<<<8, 256, 0, stream>>>(part, ln2g, ln2b, seqg);
  router_mlp1<<<dim3(16, 8, 1), 256, 0, stream>>>(seqg, rw1, pmlp);
  router_fold<<<8, 256, 0, stream>>>(pmlp, rb1, g1g);
  router_top<<<8, 256, 0, stream>>>(g1g, rw2, rb2, wslot, topk);
  // merged FFN1: shared (768 blocks) + expert (1536 blocks), K=768 uniform
  gemm_ffn1<<<2304, 256, 0, stream>>>(hbuf, shw1t, shb1, ew1t, eb1,
                                      topk, wslot, shid, hid);
  // merged FFN2: shared (192 blocks, K=3072) + expert (768 blocks, K=1536)
  gemm_ffn2<<<960, 256, 0, stream>>>(shid, shw2t, shb2, x2, hid, ew2t, eb2,
                                     topk, wslot, (float*)d_out, eo);
  combine_kernel<<<3072, 256, 0, stream>>>(eo, (float*)d_out);
}